// Round 1
// baseline (1198.600 us; speedup 1.0000x reference)
//
#include <hip/hip_runtime.h>

#define N_NODES 50000
#define E_EDGES 800000
#define E2 (E_EDGES + N_NODES)
#define HC 256
#define NHEAD 4
#define GG 128
#define DENSE 64
#define NCLS 2
#define BN_EPS 1e-5f
#define NEG_SLOPE 0.2f

// ---------------- GEMM: C[M,256] = A[M,256] @ B[256,256] (row-major) ----------------
#define BM 64
#define BN 64
#define BK 16
__global__ __launch_bounds__(256) void gemm_kernel(const float* __restrict__ A,
                                                   const float* __restrict__ B,
                                                   float* __restrict__ C, int M) {
    __shared__ float As[BK][BM + 2];
    __shared__ __align__(16) float Bs[BK][BN + 4];
    int tid = threadIdx.x;
    int tx = tid & 15, ty = tid >> 4;
    int row0 = blockIdx.x * BM;
    int col0 = blockIdx.y * BN;
    float acc[4][4] = {};
    int ar = tid >> 2;          // 0..63
    int ak = (tid & 3) << 2;    // 0,4,8,12
    int bkr = tid >> 4;         // 0..15
    int bc = (tid & 15) << 2;   // 0..60
    for (int k0 = 0; k0 < HC; k0 += BK) {
        int grow = row0 + ar;
        float4 av = make_float4(0.f, 0.f, 0.f, 0.f);
        if (grow < M) av = *reinterpret_cast<const float4*>(A + (size_t)grow * HC + k0 + ak);
        As[ak + 0][ar] = av.x; As[ak + 1][ar] = av.y;
        As[ak + 2][ar] = av.z; As[ak + 3][ar] = av.w;
        float4 bv = *reinterpret_cast<const float4*>(B + (size_t)(k0 + bkr) * HC + col0 + bc);
        *reinterpret_cast<float4*>(&Bs[bkr][bc]) = bv;
        __syncthreads();
#pragma unroll
        for (int kk = 0; kk < BK; ++kk) {
            float a0 = As[kk][ty * 4 + 0], a1 = As[kk][ty * 4 + 1];
            float a2 = As[kk][ty * 4 + 2], a3 = As[kk][ty * 4 + 3];
            float b0 = Bs[kk][tx * 4 + 0], b1 = Bs[kk][tx * 4 + 1];
            float b2 = Bs[kk][tx * 4 + 2], b3 = Bs[kk][tx * 4 + 3];
            acc[0][0] += a0 * b0; acc[0][1] += a0 * b1; acc[0][2] += a0 * b2; acc[0][3] += a0 * b3;
            acc[1][0] += a1 * b0; acc[1][1] += a1 * b1; acc[1][2] += a1 * b2; acc[1][3] += a1 * b3;
            acc[2][0] += a2 * b0; acc[2][1] += a2 * b1; acc[2][2] += a2 * b2; acc[2][3] += a2 * b3;
            acc[3][0] += a3 * b0; acc[3][1] += a3 * b1; acc[3][2] += a3 * b2; acc[3][3] += a3 * b3;
        }
        __syncthreads();
    }
#pragma unroll
    for (int i = 0; i < 4; ++i) {
        int grow = row0 + ty * 4 + i;
        if (grow < M) {
            float4 v = make_float4(acc[i][0], acc[i][1], acc[i][2], acc[i][3]);
            *reinterpret_cast<float4*>(C + (size_t)grow * HC + col0 + tx * 4) = v;
        }
    }
}

// ---------------- attention coefficients es/ed per node ----------------
__global__ __launch_bounds__(256) void esed_kernel(const float* __restrict__ h,
                                                   const float* __restrict__ avs,
                                                   const float* __restrict__ avd,
                                                   float* __restrict__ es, float* __restrict__ ed) {
    int tid = threadIdx.x;
    int lane = tid & 63, wid = tid >> 6;
    int node = blockIdx.x * 4 + wid;
    if (node >= N_NODES) return;
    int ch0 = lane * 4;
    float4 hv = *reinterpret_cast<const float4*>(h + (size_t)node * HC + ch0);
    float4 sa = *reinterpret_cast<const float4*>(avs + ch0);
    float4 da = *reinterpret_cast<const float4*>(avd + ch0);
    float vs = hv.x * sa.x + hv.y * sa.y + hv.z * sa.z + hv.w * sa.w;
    float vd = hv.x * da.x + hv.y * da.y + hv.z * da.z + hv.w * da.w;
#pragma unroll
    for (int m = 1; m < 16; m <<= 1) {
        vs += __shfl_xor(vs, m, 64);
        vd += __shfl_xor(vd, m, 64);
    }
    if ((lane & 15) == 0) {
        es[node * NHEAD + (lane >> 4)] = vs;
        ed[node * NHEAD + (lane >> 4)] = vd;
    }
}

// ---------------- CSR build ----------------
__global__ void init_deg_kernel(int* __restrict__ deg) {
    int i = blockIdx.x * blockDim.x + threadIdx.x;
    if (i < N_NODES) deg[i] = 1;  // self loop
}
__global__ void count_edges_kernel(const int* __restrict__ dst, int* __restrict__ deg) {
    int i = blockIdx.x * blockDim.x + threadIdx.x;
    if (i < E_EDGES) atomicAdd(&deg[dst[i]], 1);
}
__global__ __launch_bounds__(1024) void scan_kernel(const int* __restrict__ deg, int* __restrict__ rs) {
    __shared__ int wsum[16];
    __shared__ int carry_s;
    int tid = threadIdx.x;
    int lane = tid & 63, wid = tid >> 6;
    if (tid == 0) carry_s = 0;
    __syncthreads();
    for (int base = 0; base < N_NODES; base += 1024) {
        int i = base + tid;
        int v = (i < N_NODES) ? deg[i] : 0;
        int x = v;
#pragma unroll
        for (int off = 1; off < 64; off <<= 1) {
            int y = __shfl_up(x, off, 64);
            if (lane >= off) x += y;
        }
        if (lane == 63) wsum[wid] = x;
        __syncthreads();
        if (wid == 0) {
            int s = (lane < 16) ? wsum[lane] : 0;
#pragma unroll
            for (int off = 1; off < 16; off <<= 1) {
                int y = __shfl_up(s, off, 64);
                if (lane >= off) s += y;
            }
            if (lane < 16) wsum[lane] = s;
        }
        __syncthreads();
        int waveoff = (wid == 0) ? 0 : wsum[wid - 1];
        int carry = carry_s;
        if (i < N_NODES) rs[i] = carry + waveoff + x - v;
        __syncthreads();
        if (tid == 1023) carry_s = carry + wsum[15];
        __syncthreads();
    }
    if (tid == 0) rs[N_NODES] = carry_s;
}
__global__ void copy_cursor_kernel(const int* __restrict__ rs, int* __restrict__ cursor) {
    int i = blockIdx.x * blockDim.x + threadIdx.x;
    if (i < N_NODES) cursor[i] = rs[i];
}
__global__ void scatter_self_kernel(int* __restrict__ cursor, int* __restrict__ csr) {
    int i = blockIdx.x * blockDim.x + threadIdx.x;
    if (i < N_NODES) {
        int pos = atomicAdd(&cursor[i], 1);
        csr[pos] = i;
    }
}
__global__ void scatter_edges_kernel(const int* __restrict__ src, const int* __restrict__ dst,
                                     int* __restrict__ cursor, int* __restrict__ csr) {
    int i = blockIdx.x * blockDim.x + threadIdx.x;
    if (i < E_EDGES) {
        int pos = atomicAdd(&cursor[dst[i]], 1);
        csr[pos] = src[i];
    }
}

// ---------------- GAT aggregation: one wave per node, online softmax ----------------
__global__ __launch_bounds__(256) void gat_agg_kernel(const float* __restrict__ hlin,
                                                      const float* __restrict__ es,
                                                      const float* __restrict__ ed,
                                                      const int* __restrict__ rs,
                                                      const int* __restrict__ csr,
                                                      const float* __restrict__ bias,
                                                      float* __restrict__ out, int do_relu) {
    int tid = threadIdx.x;
    int lane = tid & 63, wid = tid >> 6;
    int node = blockIdx.x * 4 + wid;
    if (node >= N_NODES) return;
    int head = lane >> 4;
    int ch0 = lane * 4;
    float edn = ed[node * NHEAD + head];
    float m = -INFINITY, s = 0.f;
    float a0 = 0.f, a1 = 0.f, a2 = 0.f, a3 = 0.f;
    int beg = rs[node], end = rs[node + 1];
    for (int idx = beg; idx < end; ++idx) {
        int srcN = csr[idx];
        float e = es[srcN * NHEAD + head] + edn;
        e = (e >= 0.f) ? e : NEG_SLOPE * e;
        float mn = fmaxf(m, e);
        float rescale = __expf(m - mn);   // 0 when m == -inf
        float p = __expf(e - mn);
        float4 hv = *reinterpret_cast<const float4*>(hlin + (size_t)srcN * HC + ch0);
        s = s * rescale + p;
        a0 = a0 * rescale + p * hv.x;
        a1 = a1 * rescale + p * hv.y;
        a2 = a2 * rescale + p * hv.z;
        a3 = a3 * rescale + p * hv.w;
        m = mn;
    }
    float inv = 1.f / (s + 1e-16f);
    float4 bv = *reinterpret_cast<const float4*>(bias + ch0);
    float o0 = a0 * inv + bv.x, o1 = a1 * inv + bv.y;
    float o2 = a2 * inv + bv.z, o3 = a3 * inv + bv.w;
    if (do_relu) {
        o0 = fmaxf(o0, 0.f); o1 = fmaxf(o1, 0.f);
        o2 = fmaxf(o2, 0.f); o3 = fmaxf(o3, 0.f);
    }
    *reinterpret_cast<float4*>(out + (size_t)node * HC + ch0) = make_float4(o0, o1, o2, o3);
}

// ---------------- BatchNorm over N_NODES rows ----------------
__global__ __launch_bounds__(256) void bn_stats_kernel(const float* __restrict__ x,
                                                       float* __restrict__ sums, int rows_per_block) {
    int t = threadIdx.x;
    int r0 = blockIdx.x * rows_per_block;
    int r1 = min(N_NODES, r0 + rows_per_block);
    float s = 0.f, s2 = 0.f;
    for (int r = r0; r < r1; ++r) {
        float v = x[(size_t)r * HC + t];
        s += v; s2 += v * v;
    }
    atomicAdd(&sums[t], s);
    atomicAdd(&sums[HC + t], s2);
}
__global__ void bn_finalize_kernel(const float* __restrict__ sums, const float* __restrict__ g,
                                   const float* __restrict__ b, float* __restrict__ prm) {
    int t = threadIdx.x;  // 256
    float mean = sums[t] / (float)N_NODES;
    float var = sums[HC + t] / (float)N_NODES - mean * mean;
    var = fmaxf(var, 0.f);
    float scale = g[t] * rsqrtf(var + BN_EPS);
    prm[t] = scale;
    prm[HC + t] = b[t] - mean * scale;
}
__global__ __launch_bounds__(256) void bn_apply_relu_kernel(const float* __restrict__ x,
                                                            const float* __restrict__ prm,
                                                            float* __restrict__ out) {
    int i = blockIdx.x * blockDim.x + threadIdx.x;
    const int total4 = N_NODES * HC / 4;
    if (i >= total4) return;
    int c0 = (i * 4) & (HC - 1);
    float4 v = *reinterpret_cast<const float4*>(x + (size_t)i * 4);
    v.x = fmaxf(v.x * prm[c0 + 0] + prm[HC + c0 + 0], 0.f);
    v.y = fmaxf(v.y * prm[c0 + 1] + prm[HC + c0 + 1], 0.f);
    v.z = fmaxf(v.z * prm[c0 + 2] + prm[HC + c0 + 2], 0.f);
    v.w = fmaxf(v.w * prm[c0 + 3] + prm[HC + c0 + 3], 0.f);
    *reinterpret_cast<float4*>(out + (size_t)i * 4) = v;
}

// ---------------- pooling ----------------
__global__ void count_nodes_kernel(const int* __restrict__ batch, int* __restrict__ cnt) {
    int i = blockIdx.x * blockDim.x + threadIdx.x;
    if (i < N_NODES) atomicAdd(&cnt[batch[i]], 1);
}
__global__ __launch_bounds__(256) void pool_kernel(const float* __restrict__ h,
                                                   const int* __restrict__ batch,
                                                   float* __restrict__ psum, int rows_per_block) {
    int t = threadIdx.x;
    int r0 = blockIdx.x * rows_per_block;
    int r1 = min(N_NODES, r0 + rows_per_block);
    float acc = 0.f;
    int gcur = -1;
    for (int r = r0; r < r1; ++r) {
        int g = batch[r];
        if (g != gcur) {
            if (gcur >= 0) atomicAdd(&psum[gcur * HC + t], acc);
            acc = 0.f; gcur = g;
        }
        acc += h[(size_t)r * HC + t];
    }
    if (gcur >= 0) atomicAdd(&psum[gcur * HC + t], acc);
}
__global__ void pool_fin_kernel(const float* __restrict__ psum, const int* __restrict__ cnt,
                                float* __restrict__ pooled) {
    int g = blockIdx.x, t = threadIdx.x;
    float c = fmaxf((float)cnt[g], 1.f);
    pooled[g * HC + t] = psum[g * HC + t] / c;
}

// ---------------- head ----------------
__global__ __launch_bounds__(256) void bn_head_kernel(const float* __restrict__ pooled,
                                                      const float* __restrict__ g,
                                                      const float* __restrict__ b,
                                                      float* __restrict__ z) {
    int t = threadIdx.x;  // channel
    float s = 0.f, s2 = 0.f;
    for (int r = 0; r < GG; ++r) {
        float v = pooled[r * HC + t];
        s += v; s2 += v * v;
    }
    float mean = s / (float)GG;
    float var = fmaxf(s2 / (float)GG - mean * mean, 0.f);
    float scale = g[t] * rsqrtf(var + BN_EPS);
    float shift = b[t] - mean * scale;
    for (int r = 0; r < GG; ++r)
        z[r * HC + t] = pooled[r * HC + t] * scale + shift;
}
__global__ __launch_bounds__(64) void lin_relu_kernel(const float* __restrict__ X,
                                                      const float* __restrict__ W,
                                                      const float* __restrict__ b,
                                                      float* __restrict__ Y, int K) {
    __shared__ float xr[256];
    int r = blockIdx.x, t = threadIdx.x;
    for (int k = t; k < K; k += 64) xr[k] = X[r * K + k];
    __syncthreads();
    float a = b[t];
    for (int k = 0; k < K; ++k) a += xr[k] * W[k * DENSE + t];
    Y[r * DENSE + t] = fmaxf(a, 0.f);
}
__global__ __launch_bounds__(128) void lin3_softmax_kernel(const float* __restrict__ X,
                                                           const float* __restrict__ W,
                                                           const float* __restrict__ b,
                                                           float* __restrict__ out) {
    int r = threadIdx.x;  // 128 rows
    const float* xr = X + r * DENSE;
    float o0 = b[0], o1 = b[1];
    for (int k = 0; k < DENSE; ++k) {
        o0 += xr[k] * W[k * NCLS + 0];
        o1 += xr[k] * W[k * NCLS + 1];
    }
    o0 = fmaxf(o0, 0.f); o1 = fmaxf(o1, 0.f);
    float mx = fmaxf(o0, o1);
    float e0 = __expf(o0 - mx), e1 = __expf(o1 - mx);
    float inv = 1.f / (e0 + e1);
    out[r * NCLS + 0] = e0 * inv;
    out[r * NCLS + 1] = e1 * inv;
}

extern "C" void kernel_launch(void* const* d_in, const int* in_sizes, int n_in,
                              void* d_out, int out_size, void* d_ws, size_t ws_size,
                              hipStream_t stream) {
    const float* x     = (const float*)d_in[0];
    const int*   ei    = (const int*)d_in[1];
    const int*   srcp  = ei;
    const int*   dstp  = ei + E_EDGES;
    const int*   batch = (const int*)d_in[2];
    const float* W1    = (const float*)d_in[3];
    const float* as1   = (const float*)d_in[4];
    const float* ad1   = (const float*)d_in[5];
    const float* b1    = (const float*)d_in[6];
    const float* Wl    = (const float*)d_in[7];
    const float* asl   = (const float*)d_in[8];
    const float* adl   = (const float*)d_in[9];
    const float* bl    = (const float*)d_in[10];
    const float* bng   = (const float*)d_in[11];
    const float* bnb   = (const float*)d_in[12];
    const float* bn1g  = (const float*)d_in[13];
    const float* bn1b  = (const float*)d_in[14];
    const float* l1W   = (const float*)d_in[15];
    const float* l1b   = (const float*)d_in[16];
    const float* l2W   = (const float*)d_in[17];
    const float* l2b   = (const float*)d_in[18];
    const float* l3W   = (const float*)d_in[19];
    const float* l3b   = (const float*)d_in[20];

    float* outp   = (float*)d_out;            // [128,2]
    float* pooled = outp + GG * NCLS;         // [128,256]

    char* w = (char*)d_ws;
    auto alloc = [&](size_t bytes) -> void* {
        void* p = (void*)w;
        w += (bytes + 255) & ~(size_t)255;
        return p;
    };
    float* h0     = (float*)alloc(sizeof(float) * (size_t)N_NODES * HC);
    float* h1     = (float*)alloc(sizeof(float) * (size_t)N_NODES * HC);
    float* h2     = (float*)alloc(sizeof(float) * (size_t)N_NODES * HC);
    float* es     = (float*)alloc(sizeof(float) * (size_t)N_NODES * NHEAD);
    float* ed     = (float*)alloc(sizeof(float) * (size_t)N_NODES * NHEAD);
    int*   rs     = (int*)alloc(sizeof(int) * (N_NODES + 1));
    int*   deg    = (int*)alloc(sizeof(int) * N_NODES);  // reused as cursor
    int*   csr    = (int*)alloc(sizeof(int) * E2);
    float* bnsums = (float*)alloc(sizeof(float) * 2 * HC);
    float* bnprm  = (float*)alloc(sizeof(float) * 2 * HC);
    float* psum   = (float*)alloc(sizeof(float) * GG * HC);
    int*   cnt    = (int*)alloc(sizeof(int) * GG);
    float* z0     = (float*)alloc(sizeof(float) * GG * HC);
    float* z1     = (float*)alloc(sizeof(float) * GG * DENSE);
    float* z2     = (float*)alloc(sizeof(float) * GG * DENSE);

    const int nblk_nodes = (N_NODES + 255) / 256;         // 196
    const int nblk_edges = (E_EDGES + 255) / 256;         // 3125
    const int nblk_wave4 = (N_NODES + 3) / 4;             // 12500

    // ---- CSR build (fixed graph, rebuilt deterministically each call) ----
    init_deg_kernel<<<nblk_nodes, 256, 0, stream>>>(deg);
    count_edges_kernel<<<nblk_edges, 256, 0, stream>>>(dstp, deg);
    scan_kernel<<<1, 1024, 0, stream>>>(deg, rs);
    copy_cursor_kernel<<<nblk_nodes, 256, 0, stream>>>(rs, deg);
    scatter_self_kernel<<<nblk_nodes, 256, 0, stream>>>(deg, csr);
    scatter_edges_kernel<<<nblk_edges, 256, 0, stream>>>(srcp, dstp, deg, csr);

    dim3 ggrid((N_NODES + BM - 1) / BM, HC / BN);

    // ---- layer 1: h0 = relu(gat(x)) ----
    gemm_kernel<<<ggrid, 256, 0, stream>>>(x, W1, h1, N_NODES);
    esed_kernel<<<nblk_wave4, 256, 0, stream>>>(h1, as1, ad1, es, ed);
    gat_agg_kernel<<<nblk_wave4, 256, 0, stream>>>(h1, es, ed, rs, csr, b1, h0, 1);

    // ---- inner layers ----
    for (int i = 0; i < 2; ++i) {
        gemm_kernel<<<ggrid, 256, 0, stream>>>(h0, Wl + (size_t)i * HC * HC, h1, N_NODES);
        esed_kernel<<<nblk_wave4, 256, 0, stream>>>(h1, asl + i * HC, adl + i * HC, es, ed);
        gat_agg_kernel<<<nblk_wave4, 256, 0, stream>>>(h1, es, ed, rs, csr, bl + i * HC, h2, 0);
        hipMemsetAsync(bnsums, 0, sizeof(float) * 2 * HC, stream);
        bn_stats_kernel<<<nblk_nodes, 256, 0, stream>>>(h2, bnsums, 256);
        bn_finalize_kernel<<<1, 256, 0, stream>>>(bnsums, bng + i * HC, bnb + i * HC, bnprm);
        bn_apply_relu_kernel<<<(N_NODES * HC / 4 + 255) / 256, 256, 0, stream>>>(h2, bnprm, h0);
    }

    // ---- pooling ----
    hipMemsetAsync(psum, 0, sizeof(float) * GG * HC, stream);
    hipMemsetAsync(cnt, 0, sizeof(int) * GG, stream);
    count_nodes_kernel<<<nblk_nodes, 256, 0, stream>>>(batch, cnt);
    pool_kernel<<<(N_NODES + 127) / 128, 256, 0, stream>>>(h0, batch, psum, 128);
    pool_fin_kernel<<<GG, HC, 0, stream>>>(psum, cnt, pooled);

    // ---- head ----
    bn_head_kernel<<<1, HC, 0, stream>>>(pooled, bn1g, bn1b, z0);
    lin_relu_kernel<<<GG, 64, 0, stream>>>(z0, l1W, l1b, z1, HC);
    lin_relu_kernel<<<GG, 64, 0, stream>>>(z1, l2W, l2b, z2, DENSE);
    lin3_softmax_kernel<<<1, GG, 0, stream>>>(z2, l3W, l3b, outp);
}

// Round 3
// 919.257 us; speedup vs baseline: 1.3039x; 1.3039x over previous
//
#include <hip/hip_runtime.h>

#define N_NODES 50000
#define E_EDGES 800000
#define E2 (E_EDGES + N_NODES)
#define HC 256
#define NHEAD 4
#define GG 128
#define DENSE 64
#define NCLS 2
#define BN_EPS 1e-5f
#define NEG_SLOPE 0.2f

typedef __attribute__((ext_vector_type(8))) short bf16x8;
typedef __attribute__((ext_vector_type(4))) float f32x4;

__device__ __forceinline__ unsigned short f2bf(float f) {
    unsigned int u = __float_as_uint(f);
    u = (u + 0x7FFFu + ((u >> 16) & 1u)) >> 16;
    return (unsigned short)u;
}
__device__ __forceinline__ float bf2f(unsigned short h) {
    return __uint_as_float(((unsigned int)h) << 16);
}

// ---------------- fp32 -> bf16 conversion (8 elems/thread) ----------------
__global__ __launch_bounds__(256) void convert_bf16_kernel(const float* __restrict__ in,
                                                           unsigned short* __restrict__ out,
                                                           int n8) {
    int i = blockIdx.x * blockDim.x + threadIdx.x;
    if (i >= n8) return;
    const float4* p = reinterpret_cast<const float4*>(in + (size_t)i * 8);
    float4 a = p[0], b = p[1];
    ushort4 lo = make_ushort4(f2bf(a.x), f2bf(a.y), f2bf(a.z), f2bf(a.w));
    ushort4 hi = make_ushort4(f2bf(b.x), f2bf(b.y), f2bf(b.z), f2bf(b.w));
    ushort4* q = reinterpret_cast<ushort4*>(out + (size_t)i * 8);
    q[0] = lo; q[1] = hi;
}

// ---------------- pack W [256,256] fp32 into MFMA b-fragment order, bf16 ----------------
// group g = ks*16+ct (128 groups), lane l: elems W[ks*32 + (l>>4)*8 + j][ct*16 + (l&15)]
__global__ __launch_bounds__(64) void pack_b_kernel(const float* __restrict__ W,
                                                    unsigned short* __restrict__ Bpk) {
    int l = threadIdx.x;
    int g = blockIdx.x;
    int ks = g >> 4, ct = g & 15;
    int col = ct * 16 + (l & 15);
    int k0 = ks * 32 + (l >> 4) * 8;
    unsigned short v[8];
#pragma unroll
    for (int j = 0; j < 8; ++j) v[j] = f2bf(W[(size_t)(k0 + j) * HC + col]);
    ushort4* q = reinterpret_cast<ushort4*>(Bpk + ((size_t)g * 64 + l) * 8);
    q[0] = make_ushort4(v[0], v[1], v[2], v[3]);
    q[1] = make_ushort4(v[4], v[5], v[6], v[7]);
}

// ---------------- MFMA GEMM: C[M,256](bf16) = A[M,256](bf16) @ B(packed) ----------------
__global__ __launch_bounds__(256) void gemm_mfma_kernel(const unsigned short* __restrict__ A,
                                                        const unsigned short* __restrict__ Bpk,
                                                        unsigned short* __restrict__ C, int M) {
    __shared__ unsigned short As[64 * 256];  // 32 KB, XOR-swizzled rows
    int tid = threadIdx.x;
    int lane = tid & 63, wid = tid >> 6;
    int row0 = blockIdx.x * 64;
    // stage A-tile (full K): 8 x 16B per thread, coalesced
#pragma unroll
    for (int i = 0; i < 8; ++i) {
        int idx = tid + i * 256;
        int row = idx >> 5, c16 = idx & 31;
        int grow = row0 + row;
        uint4 v = make_uint4(0u, 0u, 0u, 0u);
        if (grow < M) v = *reinterpret_cast<const uint4*>(A + (size_t)grow * HC + c16 * 8);
        int byteoff = row * 512 + c16 * 16;
        byteoff ^= (row & 7) << 4;
        *reinterpret_cast<uint4*>((char*)As + byteoff) = v;
    }
    __syncthreads();

    f32x4 acc[16];
#pragma unroll
    for (int ct = 0; ct < 16; ++ct) acc[ct] = (f32x4){0.f, 0.f, 0.f, 0.f};

    int mrow = wid * 16 + (lane & 15);
#pragma unroll
    for (int ks = 0; ks < 8; ++ks) {
        int abyte = mrow * 512 + ks * 64 + (lane >> 4) * 16;
        abyte ^= (mrow & 7) << 4;
        bf16x8 a = *reinterpret_cast<const bf16x8*>((char*)As + abyte);
        // group g = ks*16 + ct; each group is 64 lanes * 8 elems = 512 elements
        const unsigned short* bp = Bpk + ((size_t)(ks * 16) * 512 + lane * 8);
#pragma unroll
        for (int ct = 0; ct < 16; ++ct) {
            bf16x8 b = *reinterpret_cast<const bf16x8*>(bp + (size_t)ct * 512);
            acc[ct] = __builtin_amdgcn_mfma_f32_16x16x32_bf16(a, b, acc[ct], 0, 0, 0);
        }
    }
    // C/D layout: col = lane&15, row = (lane>>4)*4 + r
    int crow0 = row0 + wid * 16 + (lane >> 4) * 4;
    int ccol = lane & 15;
#pragma unroll
    for (int ct = 0; ct < 16; ++ct) {
#pragma unroll
        for (int r = 0; r < 4; ++r) {
            int grow = crow0 + r;
            if (grow < M) C[(size_t)grow * HC + ct * 16 + ccol] = f2bf(acc[ct][r]);
        }
    }
}

// ---------------- attention coefficients es/ed per node (bf16 h) ----------------
__global__ __launch_bounds__(256) void esed_kernel(const unsigned short* __restrict__ h,
                                                   const float* __restrict__ avs,
                                                   const float* __restrict__ avd,
                                                   float* __restrict__ es, float* __restrict__ ed) {
    int tid = threadIdx.x;
    int lane = tid & 63, wid = tid >> 6;
    int node = blockIdx.x * 4 + wid;
    if (node >= N_NODES) return;
    int ch0 = lane * 4;
    ushort4 hv = *reinterpret_cast<const ushort4*>(h + (size_t)node * HC + ch0);
    float4 sa = *reinterpret_cast<const float4*>(avs + ch0);
    float4 da = *reinterpret_cast<const float4*>(avd + ch0);
    float h0 = bf2f(hv.x), h1 = bf2f(hv.y), h2 = bf2f(hv.z), h3 = bf2f(hv.w);
    float vs = h0 * sa.x + h1 * sa.y + h2 * sa.z + h3 * sa.w;
    float vd = h0 * da.x + h1 * da.y + h2 * da.z + h3 * da.w;
#pragma unroll
    for (int m = 1; m < 16; m <<= 1) {
        vs += __shfl_xor(vs, m, 64);
        vd += __shfl_xor(vd, m, 64);
    }
    if ((lane & 15) == 0) {
        es[node * NHEAD + (lane >> 4)] = vs;
        ed[node * NHEAD + (lane >> 4)] = vd;
    }
}

// ---------------- CSR build ----------------
__global__ void init_deg_kernel(int* __restrict__ deg) {
    int i = blockIdx.x * blockDim.x + threadIdx.x;
    if (i < N_NODES) deg[i] = 1;  // self loop
}
__global__ void count_edges_kernel(const int* __restrict__ dst, int* __restrict__ deg) {
    int i = blockIdx.x * blockDim.x + threadIdx.x;
    if (i < E_EDGES) atomicAdd(&deg[dst[i]], 1);
}
__global__ __launch_bounds__(1024) void scan1_kernel(const int* __restrict__ deg,
                                                     int* __restrict__ rs, int* __restrict__ bsum) {
    __shared__ int wsum[16];
    int t = threadIdx.x, lane = t & 63, wid = t >> 6;
    int i = blockIdx.x * 1024 + t;
    int v = (i < N_NODES) ? deg[i] : 0;
    int x = v;
#pragma unroll
    for (int off = 1; off < 64; off <<= 1) {
        int y = __shfl_up(x, off, 64);
        if (lane >= off) x += y;
    }
    if (lane == 63) wsum[wid] = x;
    __syncthreads();
    if (wid == 0) {
        int s = (lane < 16) ? wsum[lane] : 0;
#pragma unroll
        for (int off = 1; off < 16; off <<= 1) {
            int y = __shfl_up(s, off, 64);
            if (lane >= off) s += y;
        }
        if (lane < 16) wsum[lane] = s;
    }
    __syncthreads();
    int woff = wid ? wsum[wid - 1] : 0;
    if (i <= N_NODES) rs[i] = woff + x - v;
    if (t == 1023) bsum[blockIdx.x] = wsum[15];
}
__global__ void scan2_kernel(int* __restrict__ bsum, int nb) {
    int l = threadIdx.x;
    int v = (l < nb) ? bsum[l] : 0;
    int x = v;
#pragma unroll
    for (int off = 1; off < 64; off <<= 1) {
        int y = __shfl_up(x, off, 64);
        if (l >= off) x += y;
    }
    if (l < nb) bsum[l] = x - v;
}
__global__ void scan3_kernel(int* __restrict__ rs, const int* __restrict__ bsum,
                             int* __restrict__ cursor) {
    int i = blockIdx.x * blockDim.x + threadIdx.x;
    if (i <= N_NODES) {
        int v = rs[i] + bsum[i >> 10];
        rs[i] = v;
        if (i < N_NODES) cursor[i] = v;
    }
}
__global__ void scatter_self_kernel(int* __restrict__ cursor, int* __restrict__ csr) {
    int i = blockIdx.x * blockDim.x + threadIdx.x;
    if (i < N_NODES) {
        int pos = atomicAdd(&cursor[i], 1);
        csr[pos] = i;
    }
}
__global__ void scatter_edges_kernel(const int* __restrict__ src, const int* __restrict__ dst,
                                     int* __restrict__ cursor, int* __restrict__ csr) {
    int i = blockIdx.x * blockDim.x + threadIdx.x;
    if (i < E_EDGES) {
        int pos = atomicAdd(&cursor[dst[i]], 1);
        csr[pos] = src[i];
    }
}

// ---------------- softmax prep: per-node per-head (max, sumexp) ----------------
__global__ __launch_bounds__(256) void smprep_kernel(const float* __restrict__ es,
                                                     const float* __restrict__ ed,
                                                     const int* __restrict__ rs,
                                                     const int* __restrict__ csr,
                                                     float* __restrict__ ms) {
    int tid = threadIdx.x;
    int lane = tid & 63, wid = tid >> 6;
    int node = blockIdx.x * 4 + wid;
    if (node >= N_NODES) return;
    int head = lane >> 4, slot = lane & 15;
    float edn = ed[node * NHEAD + head];
    int beg = rs[node], end = rs[node + 1];
    float m = -INFINITY;
    for (int i = beg + slot; i < end; i += 16) {
        float e = es[csr[i] * NHEAD + head] + edn;
        e = (e >= 0.f) ? e : NEG_SLOPE * e;
        m = fmaxf(m, e);
    }
#pragma unroll
    for (int off = 1; off < 16; off <<= 1) m = fmaxf(m, __shfl_xor(m, off, 64));
    float s = 0.f;
    for (int i = beg + slot; i < end; i += 16) {
        float e = es[csr[i] * NHEAD + head] + edn;
        e = (e >= 0.f) ? e : NEG_SLOPE * e;
        s += __expf(e - m);
    }
#pragma unroll
    for (int off = 1; off < 16; off <<= 1) s += __shfl_xor(s, off, 64);
    if (slot == 0) {
        ms[node * 8 + head * 2] = m;
        ms[node * 8 + head * 2 + 1] = s;
    }
}

// ---------------- GAT aggregation: wave per node, fixed m/s, bf16 h ----------------
__global__ __launch_bounds__(256) void gat_agg_kernel(const unsigned short* __restrict__ hlin,
                                                      const float* __restrict__ es,
                                                      const float* __restrict__ ed,
                                                      const float* __restrict__ ms,
                                                      const int* __restrict__ rs,
                                                      const int* __restrict__ csr,
                                                      const float* __restrict__ bias,
                                                      unsigned short* __restrict__ out, int do_relu) {
    int tid = threadIdx.x;
    int lane = tid & 63, wid = tid >> 6;
    int node = blockIdx.x * 4 + wid;
    if (node >= N_NODES) return;
    int head = lane >> 4;
    int ch0 = lane * 4;
    float edn = ed[node * NHEAD + head];
    float m = ms[node * 8 + head * 2];
    float s = ms[node * 8 + head * 2 + 1];
    float inv = 1.f / (s + 1e-16f);
    float a0 = 0.f, a1 = 0.f, a2 = 0.f, a3 = 0.f;
    int beg = rs[node], end = rs[node + 1];
    for (int idx = beg; idx < end; ++idx) {
        int srcN = csr[idx];
        float e = es[srcN * NHEAD + head] + edn;
        e = (e >= 0.f) ? e : NEG_SLOPE * e;
        float p = __expf(e - m);
        ushort4 hv = *reinterpret_cast<const ushort4*>(hlin + (size_t)srcN * HC + ch0);
        a0 += p * bf2f(hv.x);
        a1 += p * bf2f(hv.y);
        a2 += p * bf2f(hv.z);
        a3 += p * bf2f(hv.w);
    }
    const float4 bv = *reinterpret_cast<const float4*>(bias + ch0);
    float o0 = a0 * inv + bv.x, o1 = a1 * inv + bv.y;
    float o2 = a2 * inv + bv.z, o3 = a3 * inv + bv.w;
    if (do_relu) {
        o0 = fmaxf(o0, 0.f); o1 = fmaxf(o1, 0.f);
        o2 = fmaxf(o2, 0.f); o3 = fmaxf(o3, 0.f);
    }
    *reinterpret_cast<ushort4*>(out + (size_t)node * HC + ch0) =
        make_ushort4(f2bf(o0), f2bf(o1), f2bf(o2), f2bf(o3));
}

// ---------------- BatchNorm over N_NODES rows (bf16 in/out) ----------------
__global__ __launch_bounds__(256) void bn_stats_kernel(const unsigned short* __restrict__ x,
                                                       float* __restrict__ sums, int rows_per_block) {
    int t = threadIdx.x;
    int r0 = blockIdx.x * rows_per_block;
    int r1 = min(N_NODES, r0 + rows_per_block);
    float s = 0.f, s2 = 0.f;
    for (int r = r0; r < r1; ++r) {
        float v = bf2f(x[(size_t)r * HC + t]);
        s += v; s2 += v * v;
    }
    atomicAdd(&sums[t], s);
    atomicAdd(&sums[HC + t], s2);
}
__global__ void bn_finalize_kernel(const float* __restrict__ sums, const float* __restrict__ g,
                                   const float* __restrict__ b, float* __restrict__ prm) {
    int t = threadIdx.x;  // 256
    float mean = sums[t] / (float)N_NODES;
    float var = sums[HC + t] / (float)N_NODES - mean * mean;
    var = fmaxf(var, 0.f);
    float scale = g[t] * rsqrtf(var + BN_EPS);
    prm[t] = scale;
    prm[HC + t] = b[t] - mean * scale;
}
__global__ __launch_bounds__(256) void bn_apply_relu_kernel(const unsigned short* __restrict__ x,
                                                            const float* __restrict__ prm,
                                                            unsigned short* __restrict__ out) {
    int i = blockIdx.x * blockDim.x + threadIdx.x;
    const int total8 = N_NODES * HC / 8;
    if (i >= total8) return;
    int c0 = (i * 8) & (HC - 1);
    const ushort4* p = reinterpret_cast<const ushort4*>(x + (size_t)i * 8);
    ushort4 va = p[0], vb = p[1];
    unsigned short o[8];
    unsigned short in[8] = {va.x, va.y, va.z, va.w, vb.x, vb.y, vb.z, vb.w};
#pragma unroll
    for (int j = 0; j < 8; ++j) {
        float v = bf2f(in[j]) * prm[c0 + j] + prm[HC + c0 + j];
        o[j] = f2bf(fmaxf(v, 0.f));
    }
    ushort4* q = reinterpret_cast<ushort4*>(out + (size_t)i * 8);
    q[0] = make_ushort4(o[0], o[1], o[2], o[3]);
    q[1] = make_ushort4(o[4], o[5], o[6], o[7]);
}

// ---------------- pooling ----------------
__global__ void count_nodes_kernel(const int* __restrict__ batch, int* __restrict__ cnt) {
    int i = blockIdx.x * blockDim.x + threadIdx.x;
    if (i < N_NODES) atomicAdd(&cnt[batch[i]], 1);
}
__global__ __launch_bounds__(256) void pool_kernel(const unsigned short* __restrict__ h,
                                                   const int* __restrict__ batch,
                                                   float* __restrict__ psum, int rows_per_block) {
    int t = threadIdx.x;
    int r0 = blockIdx.x * rows_per_block;
    int r1 = min(N_NODES, r0 + rows_per_block);
    float acc = 0.f;
    int gcur = -1;
    for (int r = r0; r < r1; ++r) {
        int g = batch[r];
        if (g != gcur) {
            if (gcur >= 0) atomicAdd(&psum[gcur * HC + t], acc);
            acc = 0.f; gcur = g;
        }
        acc += bf2f(h[(size_t)r * HC + t]);
    }
    if (gcur >= 0) atomicAdd(&psum[gcur * HC + t], acc);
}
__global__ void pool_fin_kernel(const float* __restrict__ psum, const int* __restrict__ cnt,
                                float* __restrict__ pooled) {
    int g = blockIdx.x, t = threadIdx.x;
    float c = fmaxf((float)cnt[g], 1.f);
    pooled[g * HC + t] = psum[g * HC + t] / c;
}

// ---------------- head ----------------
__global__ __launch_bounds__(256) void bn_head_kernel(const float* __restrict__ pooled,
                                                      const float* __restrict__ g,
                                                      const float* __restrict__ b,
                                                      float* __restrict__ z) {
    int t = threadIdx.x;  // channel
    float s = 0.f, s2 = 0.f;
    for (int r = 0; r < GG; ++r) {
        float v = pooled[r * HC + t];
        s += v; s2 += v * v;
    }
    float mean = s / (float)GG;
    float var = fmaxf(s2 / (float)GG - mean * mean, 0.f);
    float scale = g[t] * rsqrtf(var + BN_EPS);
    float shift = b[t] - mean * scale;
    for (int r = 0; r < GG; ++r)
        z[r * HC + t] = pooled[r * HC + t] * scale + shift;
}
__global__ __launch_bounds__(64) void lin_relu_kernel(const float* __restrict__ X,
                                                      const float* __restrict__ W,
                                                      const float* __restrict__ b,
                                                      float* __restrict__ Y, int K) {
    __shared__ float xr[256];
    int r = blockIdx.x, t = threadIdx.x;
    for (int k = t; k < K; k += 64) xr[k] = X[r * K + k];
    __syncthreads();
    float a = b[t];
    for (int k = 0; k < K; ++k) a += xr[k] * W[k * DENSE + t];
    Y[r * DENSE + t] = fmaxf(a, 0.f);
}
__global__ __launch_bounds__(128) void lin3_softmax_kernel(const float* __restrict__ X,
                                                           const float* __restrict__ W,
                                                           const float* __restrict__ b,
                                                           float* __restrict__ out) {
    int r = threadIdx.x;  // 128 rows
    const float* xr = X + r * DENSE;
    float o0 = b[0], o1 = b[1];
    for (int k = 0; k < DENSE; ++k) {
        o0 += xr[k] * W[k * NCLS + 0];
        o1 += xr[k] * W[k * NCLS + 1];
    }
    o0 = fmaxf(o0, 0.f); o1 = fmaxf(o1, 0.f);
    float mx = fmaxf(o0, o1);
    float e0 = __expf(o0 - mx), e1 = __expf(o1 - mx);
    float inv = 1.f / (e0 + e1);
    out[r * NCLS + 0] = e0 * inv;
    out[r * NCLS + 1] = e1 * inv;
}

extern "C" void kernel_launch(void* const* d_in, const int* in_sizes, int n_in,
                              void* d_out, int out_size, void* d_ws, size_t ws_size,
                              hipStream_t stream) {
    const float* x     = (const float*)d_in[0];
    const int*   ei    = (const int*)d_in[1];
    const int*   srcp  = ei;
    const int*   dstp  = ei + E_EDGES;
    const int*   batch = (const int*)d_in[2];
    const float* W1    = (const float*)d_in[3];
    const float* as1   = (const float*)d_in[4];
    const float* ad1   = (const float*)d_in[5];
    const float* b1    = (const float*)d_in[6];
    const float* Wl    = (const float*)d_in[7];
    const float* asl   = (const float*)d_in[8];
    const float* adl   = (const float*)d_in[9];
    const float* bl    = (const float*)d_in[10];
    const float* bng   = (const float*)d_in[11];
    const float* bnb   = (const float*)d_in[12];
    const float* bn1g  = (const float*)d_in[13];
    const float* bn1b  = (const float*)d_in[14];
    const float* l1W   = (const float*)d_in[15];
    const float* l1b   = (const float*)d_in[16];
    const float* l2W   = (const float*)d_in[17];
    const float* l2b   = (const float*)d_in[18];
    const float* l3W   = (const float*)d_in[19];
    const float* l3b   = (const float*)d_in[20];

    float* outp   = (float*)d_out;            // [128,2]
    float* pooled = outp + GG * NCLS;         // [128,256]

    char* w = (char*)d_ws;
    auto alloc = [&](size_t bytes) -> void* {
        void* p = (void*)w;
        w += (bytes + 255) & ~(size_t)255;
        return p;
    };
    unsigned short* xb  = (unsigned short*)alloc(sizeof(short) * (size_t)N_NODES * HC);
    unsigned short* h0  = (unsigned short*)alloc(sizeof(short) * (size_t)N_NODES * HC);
    unsigned short* h1  = (unsigned short*)alloc(sizeof(short) * (size_t)N_NODES * HC);
    unsigned short* h2  = (unsigned short*)alloc(sizeof(short) * (size_t)N_NODES * HC);
    unsigned short* Bpk = (unsigned short*)alloc(sizeof(short) * 3 * 128 * 64 * 8);
    float* es     = (float*)alloc(sizeof(float) * (size_t)N_NODES * NHEAD);
    float* ed     = (float*)alloc(sizeof(float) * (size_t)N_NODES * NHEAD);
    float* ms     = (float*)alloc(sizeof(float) * (size_t)N_NODES * 8);
    int*   rs     = (int*)alloc(sizeof(int) * (N_NODES + 1));
    int*   deg    = (int*)alloc(sizeof(int) * N_NODES);  // reused as cursor
    int*   csr    = (int*)alloc(sizeof(int) * E2);
    int*   bsum   = (int*)alloc(sizeof(int) * 64);
    float* bnsums = (float*)alloc(sizeof(float) * 2 * HC);
    float* bnprm  = (float*)alloc(sizeof(float) * 2 * HC);
    float* psum   = (float*)alloc(sizeof(float) * GG * HC);
    int*   cnt    = (int*)alloc(sizeof(int) * GG);
    float* z0     = (float*)alloc(sizeof(float) * GG * HC);
    float* z1     = (float*)alloc(sizeof(float) * GG * DENSE);
    float* z2     = (float*)alloc(sizeof(float) * GG * DENSE);

    const int nblk_nodes = (N_NODES + 255) / 256;
    const int nblk_edges = (E_EDGES + 255) / 256;
    const int nblk_wave4 = (N_NODES + 3) / 4;
    const int nscan = (N_NODES + 1023) / 1024;           // 49

    // ---- pack weights + convert x ----
    pack_b_kernel<<<128, 64, 0, stream>>>(W1, Bpk);
    pack_b_kernel<<<128, 64, 0, stream>>>(Wl, Bpk + 128 * 64 * 8);
    pack_b_kernel<<<128, 64, 0, stream>>>(Wl + (size_t)HC * HC, Bpk + 2 * 128 * 64 * 8);
    convert_bf16_kernel<<<(N_NODES * HC / 8 + 255) / 256, 256, 0, stream>>>(x, xb, N_NODES * HC / 8);

    // ---- CSR build ----
    init_deg_kernel<<<nblk_nodes, 256, 0, stream>>>(deg);
    count_edges_kernel<<<nblk_edges, 256, 0, stream>>>(dstp, deg);
    scan1_kernel<<<nscan, 1024, 0, stream>>>(deg, rs, bsum);
    scan2_kernel<<<1, 64, 0, stream>>>(bsum, nscan);
    scan3_kernel<<<(N_NODES + 256) / 256, 256, 0, stream>>>(rs, bsum, deg);
    scatter_self_kernel<<<nblk_nodes, 256, 0, stream>>>(deg, csr);
    scatter_edges_kernel<<<nblk_edges, 256, 0, stream>>>(srcp, dstp, deg, csr);

    const int ggrid = (N_NODES + 63) / 64;

    // ---- layer 1 ----
    gemm_mfma_kernel<<<ggrid, 256, 0, stream>>>(xb, Bpk, h1, N_NODES);
    esed_kernel<<<nblk_wave4, 256, 0, stream>>>(h1, as1, ad1, es, ed);
    smprep_kernel<<<nblk_wave4, 256, 0, stream>>>(es, ed, rs, csr, ms);
    gat_agg_kernel<<<nblk_wave4, 256, 0, stream>>>(h1, es, ed, ms, rs, csr, b1, h0, 1);

    // ---- inner layers ----
    for (int i = 0; i < 2; ++i) {
        gemm_mfma_kernel<<<ggrid, 256, 0, stream>>>(h0, Bpk + (size_t)(i + 1) * 128 * 64 * 8, h1, N_NODES);
        esed_kernel<<<nblk_wave4, 256, 0, stream>>>(h1, asl + i * HC, adl + i * HC, es, ed);
        smprep_kernel<<<nblk_wave4, 256, 0, stream>>>(es, ed, rs, csr, ms);
        gat_agg_kernel<<<nblk_wave4, 256, 0, stream>>>(h1, es, ed, ms, rs, csr, bl + i * HC, h2, 0);
        hipMemsetAsync(bnsums, 0, sizeof(float) * 2 * HC, stream);
        bn_stats_kernel<<<nblk_nodes, 256, 0, stream>>>(h2, bnsums, 256);
        bn_finalize_kernel<<<1, 256, 0, stream>>>(bnsums, bng + i * HC, bnb + i * HC, bnprm);
        bn_apply_relu_kernel<<<(N_NODES * HC / 8 + 255) / 256, 256, 0, stream>>>(h2, bnprm, h0);
    }

    // ---- pooling ----
    hipMemsetAsync(psum, 0, sizeof(float) * GG * HC, stream);
    hipMemsetAsync(cnt, 0, sizeof(int) * GG, stream);
    count_nodes_kernel<<<nblk_nodes, 256, 0, stream>>>(batch, cnt);
    pool_kernel<<<(N_NODES + 127) / 128, 256, 0, stream>>>(h0, batch, psum, 128);
    pool_fin_kernel<<<GG, HC, 0, stream>>>(psum, cnt, pooled);

    // ---- head ----
    bn_head_kernel<<<1, HC, 0, stream>>>(pooled, bn1g, bn1b, z0);
    lin_relu_kernel<<<GG, 64, 0, stream>>>(z0, l1W, l1b, z1, HC);
    lin_relu_kernel<<<GG, 64, 0, stream>>>(z1, l2W, l2b, z2, DENSE);
    lin3_softmax_kernel<<<1, GG, 0, stream>>>(z2, l3W, l3b, outp);
}

// Round 5
// 789.184 us; speedup vs baseline: 1.5188x; 1.1648x over previous
//
#include <hip/hip_runtime.h>

#define N_NODES 50000
#define E_EDGES 800000
#define E2 (E_EDGES + N_NODES)
#define HC 256
#define NHEAD 4
#define GG 128
#define DENSE 64
#define NCLS 2
#define BN_EPS 1e-5f
#define NEG_SLOPE 0.2f
#define NEG_BIG -1e30f

typedef __attribute__((ext_vector_type(8))) short bf16x8;
typedef __attribute__((ext_vector_type(4))) float f32x4;

__device__ __forceinline__ unsigned short f2bf(float f) {
    unsigned int u = __float_as_uint(f);
    u = (u + 0x7FFFu + ((u >> 16) & 1u)) >> 16;
    return (unsigned short)u;
}
__device__ __forceinline__ float bf2f(unsigned short h) {
    return __uint_as_float(((unsigned int)h) << 16);
}

// ---------------- fp32 -> bf16 conversion (8 elems/thread) ----------------
__global__ __launch_bounds__(256) void convert_bf16_kernel(const float* __restrict__ in,
                                                           unsigned short* __restrict__ out,
                                                           int n8) {
    int i = blockIdx.x * blockDim.x + threadIdx.x;
    if (i >= n8) return;
    const float4* p = reinterpret_cast<const float4*>(in + (size_t)i * 8);
    float4 a = p[0], b = p[1];
    ushort4 lo = make_ushort4(f2bf(a.x), f2bf(a.y), f2bf(a.z), f2bf(a.w));
    ushort4 hi = make_ushort4(f2bf(b.x), f2bf(b.y), f2bf(b.z), f2bf(b.w));
    ushort4* q = reinterpret_cast<ushort4*>(out + (size_t)i * 8);
    q[0] = lo; q[1] = hi;
}

// ---------------- pack W [256,256] fp32 into MFMA b-fragment order, bf16 ----------------
// group g = ks*16+ct (128 groups), lane l: elems W[ks*32 + (l>>4)*8 + j][ct*16 + (l&15)]
__global__ __launch_bounds__(64) void pack_b_kernel(const float* __restrict__ W,
                                                    unsigned short* __restrict__ Bpk) {
    int l = threadIdx.x;
    int g = blockIdx.x;
    int ks = g >> 4, ct = g & 15;
    int col = ct * 16 + (l & 15);
    int k0 = ks * 32 + (l >> 4) * 8;
    unsigned short v[8];
#pragma unroll
    for (int j = 0; j < 8; ++j) v[j] = f2bf(W[(size_t)(k0 + j) * HC + col]);
    ushort4* q = reinterpret_cast<ushort4*>(Bpk + ((size_t)g * 64 + l) * 8);
    q[0] = make_ushort4(v[0], v[1], v[2], v[3]);
    q[1] = make_ushort4(v[4], v[5], v[6], v[7]);
}

// ---------------- MFMA GEMM: C[M,256](bf16) = A[M,256](bf16) @ B(packed) ----------------
__global__ __launch_bounds__(256) void gemm_mfma_kernel(const unsigned short* __restrict__ A,
                                                        const unsigned short* __restrict__ Bpk,
                                                        unsigned short* __restrict__ C, int M) {
    __shared__ unsigned short As[64 * 256];  // 32 KB, XOR-swizzled rows
    int tid = threadIdx.x;
    int lane = tid & 63, wid = tid >> 6;
    int row0 = blockIdx.x * 64;
#pragma unroll
    for (int i = 0; i < 8; ++i) {
        int idx = tid + i * 256;
        int row = idx >> 5, c16 = idx & 31;
        int grow = row0 + row;
        uint4 v = make_uint4(0u, 0u, 0u, 0u);
        if (grow < M) v = *reinterpret_cast<const uint4*>(A + (size_t)grow * HC + c16 * 8);
        int byteoff = row * 512 + c16 * 16;
        byteoff ^= (row & 7) << 4;
        *reinterpret_cast<uint4*>((char*)As + byteoff) = v;
    }
    __syncthreads();

    f32x4 acc[16];
#pragma unroll
    for (int ct = 0; ct < 16; ++ct) acc[ct] = (f32x4){0.f, 0.f, 0.f, 0.f};

    int mrow = wid * 16 + (lane & 15);
#pragma unroll
    for (int ks = 0; ks < 8; ++ks) {
        int abyte = mrow * 512 + ks * 64 + (lane >> 4) * 16;
        abyte ^= (mrow & 7) << 4;
        bf16x8 a = *reinterpret_cast<const bf16x8*>((char*)As + abyte);
        // group g = ks*16 + ct; each group is 64 lanes * 8 elems = 512 elements
        const unsigned short* bp = Bpk + ((size_t)(ks * 16) * 512 + lane * 8);
#pragma unroll
        for (int ct = 0; ct < 16; ++ct) {
            bf16x8 b = *reinterpret_cast<const bf16x8*>(bp + (size_t)ct * 512);
            acc[ct] = __builtin_amdgcn_mfma_f32_16x16x32_bf16(a, b, acc[ct], 0, 0, 0);
        }
    }
    // C/D layout: col = lane&15, row = (lane>>4)*4 + r
    int crow0 = row0 + wid * 16 + (lane >> 4) * 4;
    int ccol = lane & 15;
#pragma unroll
    for (int ct = 0; ct < 16; ++ct) {
#pragma unroll
        for (int r = 0; r < 4; ++r) {
            int grow = crow0 + r;
            if (grow < M) C[(size_t)grow * HC + ct * 16 + ccol] = f2bf(acc[ct][r]);
        }
    }
}

// ---------------- attention coefficients es/ed per node (bf16 h) ----------------
__global__ __launch_bounds__(256) void esed_kernel(const unsigned short* __restrict__ h,
                                                   const float* __restrict__ avs,
                                                   const float* __restrict__ avd,
                                                   float* __restrict__ es, float* __restrict__ ed) {
    int tid = threadIdx.x;
    int lane = tid & 63, wid = tid >> 6;
    int node = blockIdx.x * 4 + wid;
    if (node >= N_NODES) return;
    int ch0 = lane * 4;
    ushort4 hv = *reinterpret_cast<const ushort4*>(h + (size_t)node * HC + ch0);
    float4 sa = *reinterpret_cast<const float4*>(avs + ch0);
    float4 da = *reinterpret_cast<const float4*>(avd + ch0);
    float h0 = bf2f(hv.x), h1 = bf2f(hv.y), h2 = bf2f(hv.z), h3 = bf2f(hv.w);
    float vs = h0 * sa.x + h1 * sa.y + h2 * sa.z + h3 * sa.w;
    float vd = h0 * da.x + h1 * da.y + h2 * da.z + h3 * da.w;
#pragma unroll
    for (int m = 1; m < 16; m <<= 1) {
        vs += __shfl_xor(vs, m, 64);
        vd += __shfl_xor(vd, m, 64);
    }
    if ((lane & 15) == 0) {
        es[node * NHEAD + (lane >> 4)] = vs;
        ed[node * NHEAD + (lane >> 4)] = vd;
    }
}

// ---------------- CSR build ----------------
__global__ void init_deg_kernel(int* __restrict__ deg) {
    int i = blockIdx.x * blockDim.x + threadIdx.x;
    if (i < N_NODES) deg[i] = 1;  // self loop
}
__global__ void count_edges_kernel(const int* __restrict__ dst, int* __restrict__ deg) {
    int i = blockIdx.x * blockDim.x + threadIdx.x;
    if (i < E_EDGES) atomicAdd(&deg[dst[i]], 1);
}
__global__ __launch_bounds__(1024) void scan1_kernel(const int* __restrict__ deg,
                                                     int* __restrict__ rs, int* __restrict__ bsum) {
    __shared__ int wsum[16];
    int t = threadIdx.x, lane = t & 63, wid = t >> 6;
    int i = blockIdx.x * 1024 + t;
    int v = (i < N_NODES) ? deg[i] : 0;
    int x = v;
#pragma unroll
    for (int off = 1; off < 64; off <<= 1) {
        int y = __shfl_up(x, off, 64);
        if (lane >= off) x += y;
    }
    if (lane == 63) wsum[wid] = x;
    __syncthreads();
    if (wid == 0) {
        int s = (lane < 16) ? wsum[lane] : 0;
#pragma unroll
        for (int off = 1; off < 16; off <<= 1) {
            int y = __shfl_up(s, off, 64);
            if (lane >= off) s += y;
        }
        if (lane < 16) wsum[lane] = s;
    }
    __syncthreads();
    int woff = wid ? wsum[wid - 1] : 0;
    if (i <= N_NODES) rs[i] = woff + x - v;
    if (t == 1023) bsum[blockIdx.x] = wsum[15];
}
__global__ void scan2_kernel(int* __restrict__ bsum, int nb) {
    int l = threadIdx.x;
    int v = (l < nb) ? bsum[l] : 0;
    int x = v;
#pragma unroll
    for (int off = 1; off < 64; off <<= 1) {
        int y = __shfl_up(x, off, 64);
        if (l >= off) x += y;
    }
    if (l < nb) bsum[l] = x - v;
}
__global__ void scan3_kernel(int* __restrict__ rs, const int* __restrict__ bsum,
                             int* __restrict__ cursor) {
    int i = blockIdx.x * blockDim.x + threadIdx.x;
    if (i <= N_NODES) {
        int v = rs[i] + bsum[i >> 10];
        rs[i] = v;
        if (i < N_NODES) cursor[i] = v;
    }
}
__global__ void scatter_self_kernel(int* __restrict__ cursor, int* __restrict__ csr) {
    int i = blockIdx.x * blockDim.x + threadIdx.x;
    if (i < N_NODES) {
        int pos = atomicAdd(&cursor[i], 1);
        csr[pos] = i;
    }
}
__global__ void scatter_edges_kernel(const int* __restrict__ src, const int* __restrict__ dst,
                                     int* __restrict__ cursor, int* __restrict__ csr) {
    int i = blockIdx.x * blockDim.x + threadIdx.x;
    if (i < E_EDGES) {
        int pos = atomicAdd(&cursor[dst[i]], 1);
        csr[pos] = src[i];
    }
}

// ---------------- softmax prep: per-node per-head (max, sumexp), single pass ----------------
__global__ __launch_bounds__(256) void smprep_kernel(const float* __restrict__ es,
                                                     const float* __restrict__ ed,
                                                     const int* __restrict__ rs,
                                                     const int* __restrict__ csr,
                                                     float* __restrict__ ms) {
    int tid = threadIdx.x;
    int lane = tid & 63, wid = tid >> 6;
    int node = blockIdx.x * 4 + wid;
    if (node >= N_NODES) return;
    int head = lane >> 4, slot = lane & 15;
    float edn = ed[node * NHEAD + head];
    int beg = rs[node], end = rs[node + 1];
    // finite sentinel: -inf would produce (-inf)-(-inf)=NaN when merging two
    // empty slots (deg<16 is common); with -1e30, exp(0)=1 but s stays 0.
    float m = NEG_BIG, s = 0.f;
    for (int i = beg + slot; i < end; i += 16) {
        float e = es[csr[i] * NHEAD + head] + edn;
        e = (e >= 0.f) ? e : NEG_SLOPE * e;
        float mn = fmaxf(m, e);
        s = s * __expf(m - mn) + __expf(e - mn);
        m = mn;
    }
#pragma unroll
    for (int off = 1; off < 16; off <<= 1) {
        float mo = __shfl_xor(m, off, 64);
        float so = __shfl_xor(s, off, 64);
        float mn = fmaxf(m, mo);
        s = s * __expf(m - mn) + so * __expf(mo - mn);
        m = mn;
    }
    if (slot == 0) {
        ms[node * 8 + head * 2] = m;
        ms[node * 8 + head * 2 + 1] = s;
    }
}

// ---------------- GAT aggregation: wave per node, fixed m/s, bf16 h ----------------
__global__ __launch_bounds__(256) void gat_agg_kernel(const unsigned short* __restrict__ hlin,
                                                      const float* __restrict__ es,
                                                      const float* __restrict__ ed,
                                                      const float* __restrict__ ms,
                                                      const int* __restrict__ rs,
                                                      const int* __restrict__ csr,
                                                      const float* __restrict__ bias,
                                                      unsigned short* __restrict__ out, int do_relu) {
    int tid = threadIdx.x;
    int lane = tid & 63, wid = tid >> 6;
    int node = blockIdx.x * 4 + wid;
    if (node >= N_NODES) return;
    int head = lane >> 4;
    int ch0 = lane * 4;
    float edn = ed[node * NHEAD + head];
    float m = ms[node * 8 + head * 2];
    float s = ms[node * 8 + head * 2 + 1];
    float inv = 1.f / (s + 1e-16f);
    float a0 = 0.f, a1 = 0.f, a2 = 0.f, a3 = 0.f;
    int beg = rs[node], end = rs[node + 1];
    for (int idx = beg; idx < end; ++idx) {
        int srcN = csr[idx];
        float e = es[srcN * NHEAD + head] + edn;
        e = (e >= 0.f) ? e : NEG_SLOPE * e;
        float p = __expf(e - m);
        ushort4 hv = *reinterpret_cast<const ushort4*>(hlin + (size_t)srcN * HC + ch0);
        a0 += p * bf2f(hv.x);
        a1 += p * bf2f(hv.y);
        a2 += p * bf2f(hv.z);
        a3 += p * bf2f(hv.w);
    }
    const float4 bv = *reinterpret_cast<const float4*>(bias + ch0);
    float o0 = a0 * inv + bv.x, o1 = a1 * inv + bv.y;
    float o2 = a2 * inv + bv.z, o3 = a3 * inv + bv.w;
    if (do_relu) {
        o0 = fmaxf(o0, 0.f); o1 = fmaxf(o1, 0.f);
        o2 = fmaxf(o2, 0.f); o3 = fmaxf(o3, 0.f);
    }
    *reinterpret_cast<ushort4*>(out + (size_t)node * HC + ch0) =
        make_ushort4(f2bf(o0), f2bf(o1), f2bf(o2), f2bf(o3));
}

// ---------------- BatchNorm over N_NODES rows (bf16 in/out) ----------------
__global__ __launch_bounds__(256) void bn_stats_kernel(const unsigned short* __restrict__ x,
                                                       float* __restrict__ sums, int rows_per_block) {
    int t = threadIdx.x;
    int r0 = blockIdx.x * rows_per_block;
    int r1 = min(N_NODES, r0 + rows_per_block);
    float s = 0.f, s2 = 0.f;
    for (int r = r0; r < r1; ++r) {
        float v = bf2f(x[(size_t)r * HC + t]);
        s += v; s2 += v * v;
    }
    atomicAdd(&sums[t], s);
    atomicAdd(&sums[HC + t], s2);
}
__global__ void bn_finalize_kernel(const float* __restrict__ sums, const float* __restrict__ g,
                                   const float* __restrict__ b, float* __restrict__ prm) {
    int t = threadIdx.x;  // 256
    float mean = sums[t] / (float)N_NODES;
    float var = sums[HC + t] / (float)N_NODES - mean * mean;
    var = fmaxf(var, 0.f);
    float scale = g[t] * rsqrtf(var + BN_EPS);
    prm[t] = scale;
    prm[HC + t] = b[t] - mean * scale;
}
__global__ __launch_bounds__(256) void bn_apply_relu_kernel(const unsigned short* __restrict__ x,
                                                            const float* __restrict__ prm,
                                                            unsigned short* __restrict__ out) {
    int i = blockIdx.x * blockDim.x + threadIdx.x;
    const int total8 = N_NODES * HC / 8;
    if (i >= total8) return;
    int c0 = (i * 8) & (HC - 1);
    const ushort4* p = reinterpret_cast<const ushort4*>(x + (size_t)i * 8);
    ushort4 va = p[0], vb = p[1];
    unsigned short o[8];
    unsigned short in[8] = {va.x, va.y, va.z, va.w, vb.x, vb.y, vb.z, vb.w};
#pragma unroll
    for (int j = 0; j < 8; ++j) {
        float v = bf2f(in[j]) * prm[c0 + j] + prm[HC + c0 + j];
        o[j] = f2bf(fmaxf(v, 0.f));
    }
    ushort4* q = reinterpret_cast<ushort4*>(out + (size_t)i * 8);
    q[0] = make_ushort4(o[0], o[1], o[2], o[3]);
    q[1] = make_ushort4(o[4], o[5], o[6], o[7]);
}

// ---------------- pooling ----------------
// batch is sorted: per-graph upper bound via binary search (no atomics)
__global__ __launch_bounds__(GG) void graph_ub_kernel(const int* __restrict__ batch,
                                                      int* __restrict__ ub) {
    int g = threadIdx.x;  // 0..127
    int lo = 0, hi = N_NODES;
    while (lo < hi) {
        int mid = (lo + hi) >> 1;
        if (batch[mid] <= g) lo = mid + 1; else hi = mid;
    }
    ub[g] = lo;
}
__global__ __launch_bounds__(256) void pool_kernel(const unsigned short* __restrict__ h,
                                                   const int* __restrict__ batch,
                                                   float* __restrict__ psum, int rows_per_block) {
    int t = threadIdx.x;
    int r0 = blockIdx.x * rows_per_block;
    int r1 = min(N_NODES, r0 + rows_per_block);
    float acc = 0.f;
    int gcur = -1;
    for (int r = r0; r < r1; ++r) {
        int g = batch[r];
        if (g != gcur) {
            if (gcur >= 0) atomicAdd(&psum[gcur * HC + t], acc);
            acc = 0.f; gcur = g;
        }
        acc += bf2f(h[(size_t)r * HC + t]);
    }
    if (gcur >= 0) atomicAdd(&psum[gcur * HC + t], acc);
}
__global__ void pool_fin_kernel(const float* __restrict__ psum, const int* __restrict__ ub,
                                float* __restrict__ pooled) {
    int g = blockIdx.x, t = threadIdx.x;
    int c = ub[g] - (g > 0 ? ub[g - 1] : 0);
    float cf = fmaxf((float)c, 1.f);
    pooled[g * HC + t] = psum[g * HC + t] / cf;
}

// ---------------- head ----------------
__global__ __launch_bounds__(256) void bn_head_kernel(const float* __restrict__ pooled,
                                                      const float* __restrict__ g,
                                                      const float* __restrict__ b,
                                                      float* __restrict__ z) {
    int t = threadIdx.x;  // channel
    float s = 0.f, s2 = 0.f;
    for (int r = 0; r < GG; ++r) {
        float v = pooled[r * HC + t];
        s += v; s2 += v * v;
    }
    float mean = s / (float)GG;
    float var = fmaxf(s2 / (float)GG - mean * mean, 0.f);
    float scale = g[t] * rsqrtf(var + BN_EPS);
    float shift = b[t] - mean * scale;
    for (int r = 0; r < GG; ++r)
        z[r * HC + t] = pooled[r * HC + t] * scale + shift;
}
__global__ __launch_bounds__(64) void lin_relu_kernel(const float* __restrict__ X,
                                                      const float* __restrict__ W,
                                                      const float* __restrict__ b,
                                                      float* __restrict__ Y, int K) {
    __shared__ float xr[256];
    int r = blockIdx.x, t = threadIdx.x;
    for (int k = t; k < K; k += 64) xr[k] = X[r * K + k];
    __syncthreads();
    float a = b[t];
    for (int k = 0; k < K; ++k) a += xr[k] * W[k * DENSE + t];
    Y[r * DENSE + t] = fmaxf(a, 0.f);
}
__global__ __launch_bounds__(128) void lin3_softmax_kernel(const float* __restrict__ X,
                                                           const float* __restrict__ W,
                                                           const float* __restrict__ b,
                                                           float* __restrict__ out) {
    int r = threadIdx.x;  // 128 rows
    const float* xr = X + r * DENSE;
    float o0 = b[0], o1 = b[1];
    for (int k = 0; k < DENSE; ++k) {
        o0 += xr[k] * W[k * NCLS + 0];
        o1 += xr[k] * W[k * NCLS + 1];
    }
    o0 = fmaxf(o0, 0.f); o1 = fmaxf(o1, 0.f);
    float mx = fmaxf(o0, o1);
    float e0 = __expf(o0 - mx), e1 = __expf(o1 - mx);
    float inv = 1.f / (e0 + e1);
    out[r * NCLS + 0] = e0 * inv;
    out[r * NCLS + 1] = e1 * inv;
}

extern "C" void kernel_launch(void* const* d_in, const int* in_sizes, int n_in,
                              void* d_out, int out_size, void* d_ws, size_t ws_size,
                              hipStream_t stream) {
    const float* x     = (const float*)d_in[0];
    const int*   ei    = (const int*)d_in[1];
    const int*   srcp  = ei;
    const int*   dstp  = ei + E_EDGES;
    const int*   batch = (const int*)d_in[2];
    const float* W1    = (const float*)d_in[3];
    const float* as1   = (const float*)d_in[4];
    const float* ad1   = (const float*)d_in[5];
    const float* b1    = (const float*)d_in[6];
    const float* Wl    = (const float*)d_in[7];
    const float* asl   = (const float*)d_in[8];
    const float* adl   = (const float*)d_in[9];
    const float* bl    = (const float*)d_in[10];
    const float* bng   = (const float*)d_in[11];
    const float* bnb   = (const float*)d_in[12];
    const float* bn1g  = (const float*)d_in[13];
    const float* bn1b  = (const float*)d_in[14];
    const float* l1W   = (const float*)d_in[15];
    const float* l1b   = (const float*)d_in[16];
    const float* l2W   = (const float*)d_in[17];
    const float* l2b   = (const float*)d_in[18];
    const float* l3W   = (const float*)d_in[19];
    const float* l3b   = (const float*)d_in[20];

    float* outp   = (float*)d_out;            // [128,2]
    float* pooled = outp + GG * NCLS;         // [128,256]

    char* w = (char*)d_ws;
    auto alloc = [&](size_t bytes) -> void* {
        void* p = (void*)w;
        w += (bytes + 255) & ~(size_t)255;
        return p;
    };
    unsigned short* xb  = (unsigned short*)alloc(sizeof(short) * (size_t)N_NODES * HC);
    unsigned short* h0  = (unsigned short*)alloc(sizeof(short) * (size_t)N_NODES * HC);
    unsigned short* h1  = (unsigned short*)alloc(sizeof(short) * (size_t)N_NODES * HC);
    unsigned short* h2  = (unsigned short*)alloc(sizeof(short) * (size_t)N_NODES * HC);
    unsigned short* Bpk = (unsigned short*)alloc(sizeof(short) * 3 * 128 * 64 * 8);
    float* es     = (float*)alloc(sizeof(float) * (size_t)N_NODES * NHEAD);
    float* ed     = (float*)alloc(sizeof(float) * (size_t)N_NODES * NHEAD);
    float* ms     = (float*)alloc(sizeof(float) * (size_t)N_NODES * 8);
    int*   rs     = (int*)alloc(sizeof(int) * (N_NODES + 1));
    int*   deg    = (int*)alloc(sizeof(int) * N_NODES);  // reused as cursor
    int*   csr    = (int*)alloc(sizeof(int) * E2);
    int*   bsum   = (int*)alloc(sizeof(int) * 64);
    float* bnsums = (float*)alloc(sizeof(float) * 2 * HC);
    float* bnprm  = (float*)alloc(sizeof(float) * 2 * HC);
    float* psum   = (float*)alloc(sizeof(float) * GG * HC);
    int*   ub     = (int*)alloc(sizeof(int) * GG);
    float* z0     = (float*)alloc(sizeof(float) * GG * HC);
    float* z1     = (float*)alloc(sizeof(float) * GG * DENSE);
    float* z2     = (float*)alloc(sizeof(float) * GG * DENSE);

    const int nblk_nodes = (N_NODES + 255) / 256;
    const int nblk_edges = (E_EDGES + 255) / 256;
    const int nblk_wave4 = (N_NODES + 3) / 4;
    const int nscan = (N_NODES + 1023) / 1024;           // 49

    // ---- pack weights + convert x ----
    pack_b_kernel<<<128, 64, 0, stream>>>(W1, Bpk);
    pack_b_kernel<<<128, 64, 0, stream>>>(Wl, Bpk + 128 * 64 * 8);
    pack_b_kernel<<<128, 64, 0, stream>>>(Wl + (size_t)HC * HC, Bpk + 2 * 128 * 64 * 8);
    convert_bf16_kernel<<<(N_NODES * HC / 8 + 255) / 256, 256, 0, stream>>>(x, xb, N_NODES * HC / 8);

    // ---- CSR build ----
    init_deg_kernel<<<nblk_nodes, 256, 0, stream>>>(deg);
    count_edges_kernel<<<nblk_edges, 256, 0, stream>>>(dstp, deg);
    scan1_kernel<<<nscan, 1024, 0, stream>>>(deg, rs, bsum);
    scan2_kernel<<<1, 64, 0, stream>>>(bsum, nscan);
    scan3_kernel<<<(N_NODES + 256) / 256, 256, 0, stream>>>(rs, bsum, deg);
    scatter_self_kernel<<<nblk_nodes, 256, 0, stream>>>(deg, csr);
    scatter_edges_kernel<<<nblk_edges, 256, 0, stream>>>(srcp, dstp, deg, csr);

    const int ggrid = (N_NODES + 63) / 64;

    // ---- layer 1 ----
    gemm_mfma_kernel<<<ggrid, 256, 0, stream>>>(xb, Bpk, h1, N_NODES);
    esed_kernel<<<nblk_wave4, 256, 0, stream>>>(h1, as1, ad1, es, ed);
    smprep_kernel<<<nblk_wave4, 256, 0, stream>>>(es, ed, rs, csr, ms);
    gat_agg_kernel<<<nblk_wave4, 256, 0, stream>>>(h1, es, ed, ms, rs, csr, b1, h0, 1);

    // ---- inner layers ----
    for (int i = 0; i < 2; ++i) {
        gemm_mfma_kernel<<<ggrid, 256, 0, stream>>>(h0, Bpk + (size_t)(i + 1) * 128 * 64 * 8, h1, N_NODES);
        esed_kernel<<<nblk_wave4, 256, 0, stream>>>(h1, asl + i * HC, adl + i * HC, es, ed);
        smprep_kernel<<<nblk_wave4, 256, 0, stream>>>(es, ed, rs, csr, ms);
        gat_agg_kernel<<<nblk_wave4, 256, 0, stream>>>(h1, es, ed, ms, rs, csr, bl + i * HC, h2, 0);
        hipMemsetAsync(bnsums, 0, sizeof(float) * 2 * HC, stream);
        bn_stats_kernel<<<nblk_nodes, 256, 0, stream>>>(h2, bnsums, 256);
        bn_finalize_kernel<<<1, 256, 0, stream>>>(bnsums, bng + i * HC, bnb + i * HC, bnprm);
        bn_apply_relu_kernel<<<(N_NODES * HC / 8 + 255) / 256, 256, 0, stream>>>(h2, bnprm, h0);
    }

    // ---- pooling ----
    hipMemsetAsync(psum, 0, sizeof(float) * GG * HC, stream);
    graph_ub_kernel<<<1, GG, 0, stream>>>(batch, ub);
    pool_kernel<<<(N_NODES + 127) / 128, 256, 0, stream>>>(h0, batch, psum, 128);
    pool_fin_kernel<<<GG, HC, 0, stream>>>(psum, ub, pooled);

    // ---- head ----
    bn_head_kernel<<<1, HC, 0, stream>>>(pooled, bn1g, bn1b, z0);
    lin_relu_kernel<<<GG, 64, 0, stream>>>(z0, l1W, l1b, z1, HC);
    lin_relu_kernel<<<GG, 64, 0, stream>>>(z1, l2W, l2b, z2, DENSE);
    lin3_softmax_kernel<<<1, GG, 0, stream>>>(z2, l3W, l3b, outp);
}

// Round 6
// 709.144 us; speedup vs baseline: 1.6902x; 1.1129x over previous
//
#include <hip/hip_runtime.h>

#define N_NODES 50000
#define E_EDGES 800000
#define E2 (E_EDGES + N_NODES)
#define HC 256
#define NHEAD 4
#define GG 128
#define DENSE 64
#define NCLS 2
#define BN_EPS 1e-5f
#define NEG_SLOPE 0.2f
#define NEG_BIG -1e30f

typedef __attribute__((ext_vector_type(8))) short bf16x8;
typedef __attribute__((ext_vector_type(4))) float f32x4;

__device__ __forceinline__ unsigned short f2bf(float f) {
    unsigned int u = __float_as_uint(f);
    u = (u + 0x7FFFu + ((u >> 16) & 1u)) >> 16;
    return (unsigned short)u;
}
__device__ __forceinline__ float bf2f(unsigned short h) {
    return __uint_as_float(((unsigned int)h) << 16);
}

// ---------------- fp32 -> bf16 conversion (8 elems/thread) ----------------
__global__ __launch_bounds__(256) void convert_bf16_kernel(const float* __restrict__ in,
                                                           unsigned short* __restrict__ out,
                                                           int n8) {
    int i = blockIdx.x * blockDim.x + threadIdx.x;
    if (i >= n8) return;
    const float4* p = reinterpret_cast<const float4*>(in + (size_t)i * 8);
    float4 a = p[0], b = p[1];
    ushort4 lo = make_ushort4(f2bf(a.x), f2bf(a.y), f2bf(a.z), f2bf(a.w));
    ushort4 hi = make_ushort4(f2bf(b.x), f2bf(b.y), f2bf(b.z), f2bf(b.w));
    ushort4* q = reinterpret_cast<ushort4*>(out + (size_t)i * 8);
    q[0] = lo; q[1] = hi;
}

// ---------------- pack W [256,256] fp32 into MFMA b-fragment order, bf16 ----------------
// group g = ks*16+ct (128 groups), lane l: elems W[ks*32 + (l>>4)*8 + j][ct*16 + (l&15)]
__global__ __launch_bounds__(64) void pack_b_kernel(const float* __restrict__ W,
                                                    unsigned short* __restrict__ Bpk) {
    int l = threadIdx.x;
    int g = blockIdx.x;
    int ks = g >> 4, ct = g & 15;
    int col = ct * 16 + (l & 15);
    int k0 = ks * 32 + (l >> 4) * 8;
    unsigned short v[8];
#pragma unroll
    for (int j = 0; j < 8; ++j) v[j] = f2bf(W[(size_t)(k0 + j) * HC + col]);
    ushort4* q = reinterpret_cast<ushort4*>(Bpk + ((size_t)g * 64 + l) * 8);
    q[0] = make_ushort4(v[0], v[1], v[2], v[3]);
    q[1] = make_ushort4(v[4], v[5], v[6], v[7]);
}

// ---------------- MFMA GEMM: C[M,256](bf16) = A[M,256](bf16) @ B(packed) ----------------
__global__ __launch_bounds__(256) void gemm_mfma_kernel(const unsigned short* __restrict__ A,
                                                        const unsigned short* __restrict__ Bpk,
                                                        unsigned short* __restrict__ C, int M) {
    __shared__ unsigned short As[64 * 256];  // 32 KB, XOR-swizzled rows
    int tid = threadIdx.x;
    int lane = tid & 63, wid = tid >> 6;
    int row0 = blockIdx.x * 64;
#pragma unroll
    for (int i = 0; i < 8; ++i) {
        int idx = tid + i * 256;
        int row = idx >> 5, c16 = idx & 31;
        int grow = row0 + row;
        uint4 v = make_uint4(0u, 0u, 0u, 0u);
        if (grow < M) v = *reinterpret_cast<const uint4*>(A + (size_t)grow * HC + c16 * 8);
        int byteoff = row * 512 + c16 * 16;
        byteoff ^= (row & 7) << 4;
        *reinterpret_cast<uint4*>((char*)As + byteoff) = v;
    }
    __syncthreads();

    f32x4 acc[16];
#pragma unroll
    for (int ct = 0; ct < 16; ++ct) acc[ct] = (f32x4){0.f, 0.f, 0.f, 0.f};

    int mrow = wid * 16 + (lane & 15);
#pragma unroll
    for (int ks = 0; ks < 8; ++ks) {
        int abyte = mrow * 512 + ks * 64 + (lane >> 4) * 16;
        abyte ^= (mrow & 7) << 4;
        bf16x8 a = *reinterpret_cast<const bf16x8*>((char*)As + abyte);
        // group g = ks*16 + ct; each group is 64 lanes * 8 elems = 512 elements
        const unsigned short* bp = Bpk + ((size_t)(ks * 16) * 512 + lane * 8);
#pragma unroll
        for (int ct = 0; ct < 16; ++ct) {
            bf16x8 b = *reinterpret_cast<const bf16x8*>(bp + (size_t)ct * 512);
            acc[ct] = __builtin_amdgcn_mfma_f32_16x16x32_bf16(a, b, acc[ct], 0, 0, 0);
        }
    }
    // C/D layout: col = lane&15, row = (lane>>4)*4 + r
    int crow0 = row0 + wid * 16 + (lane >> 4) * 4;
    int ccol = lane & 15;
#pragma unroll
    for (int ct = 0; ct < 16; ++ct) {
#pragma unroll
        for (int r = 0; r < 4; ++r) {
            int grow = crow0 + r;
            if (grow < M) C[(size_t)grow * HC + ct * 16 + ccol] = f2bf(acc[ct][r]);
        }
    }
}

// ---------------- attention coefficients es/ed per node (bf16 h) ----------------
__global__ __launch_bounds__(256) void esed_kernel(const unsigned short* __restrict__ h,
                                                   const float* __restrict__ avs,
                                                   const float* __restrict__ avd,
                                                   float* __restrict__ es, float* __restrict__ ed) {
    int tid = threadIdx.x;
    int lane = tid & 63, wid = tid >> 6;
    int node = blockIdx.x * 4 + wid;
    if (node >= N_NODES) return;
    int ch0 = lane * 4;
    ushort4 hv = *reinterpret_cast<const ushort4*>(h + (size_t)node * HC + ch0);
    float4 sa = *reinterpret_cast<const float4*>(avs + ch0);
    float4 da = *reinterpret_cast<const float4*>(avd + ch0);
    float h0 = bf2f(hv.x), h1 = bf2f(hv.y), h2 = bf2f(hv.z), h3 = bf2f(hv.w);
    float vs = h0 * sa.x + h1 * sa.y + h2 * sa.z + h3 * sa.w;
    float vd = h0 * da.x + h1 * da.y + h2 * da.z + h3 * da.w;
#pragma unroll
    for (int m = 1; m < 16; m <<= 1) {
        vs += __shfl_xor(vs, m, 64);
        vd += __shfl_xor(vd, m, 64);
    }
    if ((lane & 15) == 0) {
        es[node * NHEAD + (lane >> 4)] = vs;
        ed[node * NHEAD + (lane >> 4)] = vd;
    }
}

// ---------------- CSR build ----------------
__global__ void init_deg_kernel(int* __restrict__ deg) {
    int i = blockIdx.x * blockDim.x + threadIdx.x;
    if (i < N_NODES) deg[i] = 1;  // self loop
}
__global__ void count_edges_kernel(const int* __restrict__ dst, int* __restrict__ deg) {
    int i = blockIdx.x * blockDim.x + threadIdx.x;
    if (i < E_EDGES) atomicAdd(&deg[dst[i]], 1);
}
__global__ __launch_bounds__(1024) void scan1_kernel(const int* __restrict__ deg,
                                                     int* __restrict__ rs, int* __restrict__ bsum) {
    __shared__ int wsum[16];
    int t = threadIdx.x, lane = t & 63, wid = t >> 6;
    int i = blockIdx.x * 1024 + t;
    int v = (i < N_NODES) ? deg[i] : 0;
    int x = v;
#pragma unroll
    for (int off = 1; off < 64; off <<= 1) {
        int y = __shfl_up(x, off, 64);
        if (lane >= off) x += y;
    }
    if (lane == 63) wsum[wid] = x;
    __syncthreads();
    if (wid == 0) {
        int s = (lane < 16) ? wsum[lane] : 0;
#pragma unroll
        for (int off = 1; off < 16; off <<= 1) {
            int y = __shfl_up(s, off, 64);
            if (lane >= off) s += y;
        }
        if (lane < 16) wsum[lane] = s;
    }
    __syncthreads();
    int woff = wid ? wsum[wid - 1] : 0;
    if (i <= N_NODES) rs[i] = woff + x - v;
    if (t == 1023) bsum[blockIdx.x] = wsum[15];
}
__global__ void scan2_kernel(int* __restrict__ bsum, int nb) {
    int l = threadIdx.x;
    int v = (l < nb) ? bsum[l] : 0;
    int x = v;
#pragma unroll
    for (int off = 1; off < 64; off <<= 1) {
        int y = __shfl_up(x, off, 64);
        if (l >= off) x += y;
    }
    if (l < nb) bsum[l] = x - v;
}
__global__ void scan3_kernel(int* __restrict__ rs, const int* __restrict__ bsum,
                             int* __restrict__ cursor) {
    int i = blockIdx.x * blockDim.x + threadIdx.x;
    if (i <= N_NODES) {
        int v = rs[i] + bsum[i >> 10];
        rs[i] = v;
        if (i < N_NODES) cursor[i] = v;
    }
}
__global__ void scatter_self_kernel(int* __restrict__ cursor, int* __restrict__ csr) {
    int i = blockIdx.x * blockDim.x + threadIdx.x;
    if (i < N_NODES) {
        int pos = atomicAdd(&cursor[i], 1);
        csr[pos] = i;
    }
}
__global__ void scatter_edges_kernel(const int* __restrict__ src, const int* __restrict__ dst,
                                     int* __restrict__ cursor, int* __restrict__ csr) {
    int i = blockIdx.x * blockDim.x + threadIdx.x;
    if (i < E_EDGES) {
        int pos = atomicAdd(&cursor[dst[i]], 1);
        csr[pos] = src[i];
    }
}

// ---------------- softmax prep: per-node per-head (m,s) + per-edge normalized alpha ----------------
__global__ __launch_bounds__(256) void smprep_kernel(const float* __restrict__ es,
                                                     const float* __restrict__ ed,
                                                     const int* __restrict__ rs,
                                                     const int* __restrict__ csr,
                                                     float* __restrict__ alpha) {
    int tid = threadIdx.x;
    int lane = tid & 63, wid = tid >> 6;
    int node = blockIdx.x * 4 + wid;
    if (node >= N_NODES) return;
    int head = lane >> 4, slot = lane & 15;
    float edn = ed[node * NHEAD + head];
    int beg = rs[node], end = rs[node + 1];
    // finite sentinel: -inf would produce NaN on empty-slot merges (deg<16 common)
    float m = NEG_BIG, s = 0.f;
    for (int i = beg + slot; i < end; i += 16) {
        float e = es[csr[i] * NHEAD + head] + edn;
        e = (e >= 0.f) ? e : NEG_SLOPE * e;
        float mn = fmaxf(m, e);
        s = s * __expf(m - mn) + __expf(e - mn);
        m = mn;
    }
#pragma unroll
    for (int off = 1; off < 16; off <<= 1) {  // merge within head group (low 4 bits)
        float mo = __shfl_xor(m, off, 64);
        float so = __shfl_xor(s, off, 64);
        float mn = fmaxf(m, mo);
        s = s * __expf(m - mn) + so * __expf(mo - mn);
        m = mn;
    }
    // every lane now holds merged (m, s) for its head
    float inv = 1.f / (s + 1e-16f);
    for (int i = beg + slot; i < end; i += 16) {
        float e = es[csr[i] * NHEAD + head] + edn;
        e = (e >= 0.f) ? e : NEG_SLOPE * e;
        alpha[(size_t)i * NHEAD + head] = __expf(e - m) * inv;
    }
}

// ---------------- GAT aggregation: wave per node, precomputed alpha, bf16 h ----------------
__global__ __launch_bounds__(256) void gat_agg_kernel(const unsigned short* __restrict__ hlin,
                                                      const float* __restrict__ alpha,
                                                      const int* __restrict__ rs,
                                                      const int* __restrict__ csr,
                                                      const float* __restrict__ bias,
                                                      unsigned short* __restrict__ out, int do_relu) {
    int tid = threadIdx.x;
    int lane = tid & 63, wid = tid >> 6;
    int node = blockIdx.x * 4 + wid;
    if (node >= N_NODES) return;
    int head = lane >> 4;
    int ch0 = lane * 4;
    float a0 = 0.f, a1 = 0.f, a2 = 0.f, a3 = 0.f;
    int beg = rs[node], end = rs[node + 1];
    int idx = beg;
    for (; idx + 2 <= end; idx += 2) {
        int s0 = csr[idx], s1 = csr[idx + 1];
        float p0 = alpha[(size_t)idx * NHEAD + head];
        float p1 = alpha[(size_t)(idx + 1) * NHEAD + head];
        ushort4 hv0 = *reinterpret_cast<const ushort4*>(hlin + (size_t)s0 * HC + ch0);
        ushort4 hv1 = *reinterpret_cast<const ushort4*>(hlin + (size_t)s1 * HC + ch0);
        a0 += p0 * bf2f(hv0.x) + p1 * bf2f(hv1.x);
        a1 += p0 * bf2f(hv0.y) + p1 * bf2f(hv1.y);
        a2 += p0 * bf2f(hv0.z) + p1 * bf2f(hv1.z);
        a3 += p0 * bf2f(hv0.w) + p1 * bf2f(hv1.w);
    }
    if (idx < end) {
        int s0 = csr[idx];
        float p0 = alpha[(size_t)idx * NHEAD + head];
        ushort4 hv0 = *reinterpret_cast<const ushort4*>(hlin + (size_t)s0 * HC + ch0);
        a0 += p0 * bf2f(hv0.x);
        a1 += p0 * bf2f(hv0.y);
        a2 += p0 * bf2f(hv0.z);
        a3 += p0 * bf2f(hv0.w);
    }
    const float4 bv = *reinterpret_cast<const float4*>(bias + ch0);
    float o0 = a0 + bv.x, o1 = a1 + bv.y;
    float o2 = a2 + bv.z, o3 = a3 + bv.w;
    if (do_relu) {
        o0 = fmaxf(o0, 0.f); o1 = fmaxf(o1, 0.f);
        o2 = fmaxf(o2, 0.f); o3 = fmaxf(o3, 0.f);
    }
    *reinterpret_cast<ushort4*>(out + (size_t)node * HC + ch0) =
        make_ushort4(f2bf(o0), f2bf(o1), f2bf(o2), f2bf(o3));
}

// ---------------- BatchNorm over N_NODES rows (bf16 in/out) ----------------
__global__ __launch_bounds__(256) void bn_stats_kernel(const unsigned short* __restrict__ x,
                                                       float* __restrict__ sums, int rows_per_block) {
    int t = threadIdx.x;
    int r0 = blockIdx.x * rows_per_block;
    int r1 = min(N_NODES, r0 + rows_per_block);
    float s = 0.f, s2 = 0.f;
    for (int r = r0; r < r1; ++r) {
        float v = bf2f(x[(size_t)r * HC + t]);
        s += v; s2 += v * v;
    }
    atomicAdd(&sums[t], s);
    atomicAdd(&sums[HC + t], s2);
}
__global__ void bn_finalize_kernel(const float* __restrict__ sums, const float* __restrict__ g,
                                   const float* __restrict__ b, float* __restrict__ prm) {
    int t = threadIdx.x;  // 256
    float mean = sums[t] / (float)N_NODES;
    float var = sums[HC + t] / (float)N_NODES - mean * mean;
    var = fmaxf(var, 0.f);
    float scale = g[t] * rsqrtf(var + BN_EPS);
    prm[t] = scale;
    prm[HC + t] = b[t] - mean * scale;
}
__global__ __launch_bounds__(256) void bn_apply_relu_kernel(const unsigned short* __restrict__ x,
                                                            const float* __restrict__ prm,
                                                            unsigned short* __restrict__ out) {
    int i = blockIdx.x * blockDim.x + threadIdx.x;
    const int total8 = N_NODES * HC / 8;
    if (i >= total8) return;
    int c0 = (i * 8) & (HC - 1);
    const ushort4* p = reinterpret_cast<const ushort4*>(x + (size_t)i * 8);
    ushort4 va = p[0], vb = p[1];
    unsigned short o[8];
    unsigned short in[8] = {va.x, va.y, va.z, va.w, vb.x, vb.y, vb.z, vb.w};
#pragma unroll
    for (int j = 0; j < 8; ++j) {
        float v = bf2f(in[j]) * prm[c0 + j] + prm[HC + c0 + j];
        o[j] = f2bf(fmaxf(v, 0.f));
    }
    ushort4* q = reinterpret_cast<ushort4*>(out + (size_t)i * 8);
    q[0] = make_ushort4(o[0], o[1], o[2], o[3]);
    q[1] = make_ushort4(o[4], o[5], o[6], o[7]);
}

// ---------------- pooling ----------------
// batch is sorted: per-graph upper bound via binary search (no atomics)
__global__ __launch_bounds__(GG) void graph_ub_kernel(const int* __restrict__ batch,
                                                      int* __restrict__ ub) {
    int g = threadIdx.x;  // 0..127
    int lo = 0, hi = N_NODES;
    while (lo < hi) {
        int mid = (lo + hi) >> 1;
        if (batch[mid] <= g) lo = mid + 1; else hi = mid;
    }
    ub[g] = lo;
}
__global__ __launch_bounds__(256) void pool_kernel(const unsigned short* __restrict__ h,
                                                   const int* __restrict__ batch,
                                                   float* __restrict__ psum, int rows_per_block) {
    int t = threadIdx.x;
    int r0 = blockIdx.x * rows_per_block;
    int r1 = min(N_NODES, r0 + rows_per_block);
    float acc = 0.f;
    int gcur = -1;
    for (int r = r0; r < r1; ++r) {
        int g = batch[r];
        if (g != gcur) {
            if (gcur >= 0) atomicAdd(&psum[gcur * HC + t], acc);
            acc = 0.f; gcur = g;
        }
        acc += bf2f(h[(size_t)r * HC + t]);
    }
    if (gcur >= 0) atomicAdd(&psum[gcur * HC + t], acc);
}
__global__ void pool_fin_kernel(const float* __restrict__ psum, const int* __restrict__ ub,
                                float* __restrict__ pooled) {
    int g = blockIdx.x, t = threadIdx.x;
    int c = ub[g] - (g > 0 ? ub[g - 1] : 0);
    float cf = fmaxf((float)c, 1.f);
    pooled[g * HC + t] = psum[g * HC + t] / cf;
}

// ---------------- head ----------------
__global__ __launch_bounds__(256) void bn_head_kernel(const float* __restrict__ pooled,
                                                      const float* __restrict__ g,
                                                      const float* __restrict__ b,
                                                      float* __restrict__ z) {
    int t = threadIdx.x;  // channel
    float s = 0.f, s2 = 0.f;
    for (int r = 0; r < GG; ++r) {
        float v = pooled[r * HC + t];
        s += v; s2 += v * v;
    }
    float mean = s / (float)GG;
    float var = fmaxf(s2 / (float)GG - mean * mean, 0.f);
    float scale = g[t] * rsqrtf(var + BN_EPS);
    float shift = b[t] - mean * scale;
    for (int r = 0; r < GG; ++r)
        z[r * HC + t] = pooled[r * HC + t] * scale + shift;
}
__global__ __launch_bounds__(64) void lin_relu_kernel(const float* __restrict__ X,
                                                      const float* __restrict__ W,
                                                      const float* __restrict__ b,
                                                      float* __restrict__ Y, int K) {
    __shared__ float xr[256];
    int r = blockIdx.x, t = threadIdx.x;
    for (int k = t; k < K; k += 64) xr[k] = X[r * K + k];
    __syncthreads();
    float a = b[t];
    for (int k = 0; k < K; ++k) a += xr[k] * W[k * DENSE + t];
    Y[r * DENSE + t] = fmaxf(a, 0.f);
}
__global__ __launch_bounds__(128) void lin3_softmax_kernel(const float* __restrict__ X,
                                                           const float* __restrict__ W,
                                                           const float* __restrict__ b,
                                                           float* __restrict__ out) {
    int r = threadIdx.x;  // 128 rows
    const float* xr = X + r * DENSE;
    float o0 = b[0], o1 = b[1];
    for (int k = 0; k < DENSE; ++k) {
        o0 += xr[k] * W[k * NCLS + 0];
        o1 += xr[k] * W[k * NCLS + 1];
    }
    o0 = fmaxf(o0, 0.f); o1 = fmaxf(o1, 0.f);
    float mx = fmaxf(o0, o1);
    float e0 = __expf(o0 - mx), e1 = __expf(o1 - mx);
    float inv = 1.f / (e0 + e1);
    out[r * NCLS + 0] = e0 * inv;
    out[r * NCLS + 1] = e1 * inv;
}

extern "C" void kernel_launch(void* const* d_in, const int* in_sizes, int n_in,
                              void* d_out, int out_size, void* d_ws, size_t ws_size,
                              hipStream_t stream) {
    const float* x     = (const float*)d_in[0];
    const int*   ei    = (const int*)d_in[1];
    const int*   srcp  = ei;
    const int*   dstp  = ei + E_EDGES;
    const int*   batch = (const int*)d_in[2];
    const float* W1    = (const float*)d_in[3];
    const float* as1   = (const float*)d_in[4];
    const float* ad1   = (const float*)d_in[5];
    const float* b1    = (const float*)d_in[6];
    const float* Wl    = (const float*)d_in[7];
    const float* asl   = (const float*)d_in[8];
    const float* adl   = (const float*)d_in[9];
    const float* bl    = (const float*)d_in[10];
    const float* bng   = (const float*)d_in[11];
    const float* bnb   = (const float*)d_in[12];
    const float* bn1g  = (const float*)d_in[13];
    const float* bn1b  = (const float*)d_in[14];
    const float* l1W   = (const float*)d_in[15];
    const float* l1b   = (const float*)d_in[16];
    const float* l2W   = (const float*)d_in[17];
    const float* l2b   = (const float*)d_in[18];
    const float* l3W   = (const float*)d_in[19];
    const float* l3b   = (const float*)d_in[20];

    float* outp   = (float*)d_out;            // [128,2]
    float* pooled = outp + GG * NCLS;         // [128,256]

    char* w = (char*)d_ws;
    auto alloc = [&](size_t bytes) -> void* {
        void* p = (void*)w;
        w += (bytes + 255) & ~(size_t)255;
        return p;
    };
    unsigned short* xb  = (unsigned short*)alloc(sizeof(short) * (size_t)N_NODES * HC);
    unsigned short* h0  = (unsigned short*)alloc(sizeof(short) * (size_t)N_NODES * HC);
    unsigned short* h1  = (unsigned short*)alloc(sizeof(short) * (size_t)N_NODES * HC);
    unsigned short* h2  = (unsigned short*)alloc(sizeof(short) * (size_t)N_NODES * HC);
    unsigned short* Bpk = (unsigned short*)alloc(sizeof(short) * 3 * 128 * 64 * 8);
    float* es     = (float*)alloc(sizeof(float) * (size_t)N_NODES * NHEAD);
    float* ed     = (float*)alloc(sizeof(float) * (size_t)N_NODES * NHEAD);
    float* alpha  = (float*)alloc(sizeof(float) * (size_t)E2 * NHEAD);
    int*   rs     = (int*)alloc(sizeof(int) * (N_NODES + 1));
    int*   deg    = (int*)alloc(sizeof(int) * N_NODES);  // reused as cursor
    int*   csr    = (int*)alloc(sizeof(int) * E2);
    int*   bsum   = (int*)alloc(sizeof(int) * 64);
    float* bnsums = (float*)alloc(sizeof(float) * 2 * HC);
    float* bnprm  = (float*)alloc(sizeof(float) * 2 * HC);
    float* psum   = (float*)alloc(sizeof(float) * GG * HC);
    int*   ub     = (int*)alloc(sizeof(int) * GG);
    float* z0     = (float*)alloc(sizeof(float) * GG * HC);
    float* z1     = (float*)alloc(sizeof(float) * GG * DENSE);
    float* z2     = (float*)alloc(sizeof(float) * GG * DENSE);

    const int nblk_nodes = (N_NODES + 255) / 256;
    const int nblk_edges = (E_EDGES + 255) / 256;
    const int nblk_wave4 = (N_NODES + 3) / 4;
    const int nscan = (N_NODES + 1023) / 1024;           // 49

    // ---- pack weights + convert x ----
    pack_b_kernel<<<128, 64, 0, stream>>>(W1, Bpk);
    pack_b_kernel<<<128, 64, 0, stream>>>(Wl, Bpk + 128 * 64 * 8);
    pack_b_kernel<<<128, 64, 0, stream>>>(Wl + (size_t)HC * HC, Bpk + 2 * 128 * 64 * 8);
    convert_bf16_kernel<<<(N_NODES * HC / 8 + 255) / 256, 256, 0, stream>>>(x, xb, N_NODES * HC / 8);

    // ---- CSR build ----
    init_deg_kernel<<<nblk_nodes, 256, 0, stream>>>(deg);
    count_edges_kernel<<<nblk_edges, 256, 0, stream>>>(dstp, deg);
    scan1_kernel<<<nscan, 1024, 0, stream>>>(deg, rs, bsum);
    scan2_kernel<<<1, 64, 0, stream>>>(bsum, nscan);
    scan3_kernel<<<(N_NODES + 256) / 256, 256, 0, stream>>>(rs, bsum, deg);
    scatter_self_kernel<<<nblk_nodes, 256, 0, stream>>>(deg, csr);
    scatter_edges_kernel<<<nblk_edges, 256, 0, stream>>>(srcp, dstp, deg, csr);

    const int ggrid = (N_NODES + 63) / 64;

    // ---- layer 1 ----
    gemm_mfma_kernel<<<ggrid, 256, 0, stream>>>(xb, Bpk, h1, N_NODES);
    esed_kernel<<<nblk_wave4, 256, 0, stream>>>(h1, as1, ad1, es, ed);
    smprep_kernel<<<nblk_wave4, 256, 0, stream>>>(es, ed, rs, csr, alpha);
    gat_agg_kernel<<<nblk_wave4, 256, 0, stream>>>(h1, alpha, rs, csr, b1, h0, 1);

    // ---- inner layers ----
    for (int i = 0; i < 2; ++i) {
        gemm_mfma_kernel<<<ggrid, 256, 0, stream>>>(h0, Bpk + (size_t)(i + 1) * 128 * 64 * 8, h1, N_NODES);
        esed_kernel<<<nblk_wave4, 256, 0, stream>>>(h1, asl + i * HC, adl + i * HC, es, ed);
        smprep_kernel<<<nblk_wave4, 256, 0, stream>>>(es, ed, rs, csr, alpha);
        gat_agg_kernel<<<nblk_wave4, 256, 0, stream>>>(h1, alpha, rs, csr, bl + i * HC, h2, 0);
        hipMemsetAsync(bnsums, 0, sizeof(float) * 2 * HC, stream);
        bn_stats_kernel<<<nblk_nodes, 256, 0, stream>>>(h2, bnsums, 256);
        bn_finalize_kernel<<<1, 256, 0, stream>>>(bnsums, bng + i * HC, bnb + i * HC, bnprm);
        bn_apply_relu_kernel<<<(N_NODES * HC / 8 + 255) / 256, 256, 0, stream>>>(h2, bnprm, h0);
    }

    // ---- pooling ----
    hipMemsetAsync(psum, 0, sizeof(float) * GG * HC, stream);
    graph_ub_kernel<<<1, GG, 0, stream>>>(batch, ub);
    pool_kernel<<<(N_NODES + 127) / 128, 256, 0, stream>>>(h0, batch, psum, 128);
    pool_fin_kernel<<<GG, HC, 0, stream>>>(psum, ub, pooled);

    // ---- head ----
    bn_head_kernel<<<1, HC, 0, stream>>>(pooled, bn1g, bn1b, z0);
    lin_relu_kernel<<<GG, 64, 0, stream>>>(z0, l1W, l1b, z1, HC);
    lin_relu_kernel<<<GG, 64, 0, stream>>>(z1, l2W, l2b, z2, DENSE);
    lin3_softmax_kernel<<<1, GG, 0, stream>>>(z2, l3W, l3b, outp);
}